// Round 15
// baseline (664.193 us; speedup 1.0000x reference)
//
#include <hip/hip_runtime.h>
#include <hip/hip_bf16.h>
#include <math.h>

typedef unsigned short u16;
typedef unsigned int   u32;
typedef __attribute__((ext_vector_type(8))) short s8v;    // 8 x bf16
typedef __attribute__((ext_vector_type(8))) unsigned short u16x8;
typedef __attribute__((ext_vector_type(4))) float f4v;    // MFMA accumulator

#define NUU 50000
#define NTT 100000
#define EE  100000
#define DD  128
#define HH  4
#define HCC 512
#define BU  391
#define BT  782

// ---------- helpers ----------
__device__ __forceinline__ float bflo(u32 u) { return __uint_as_float(u << 16); }
__device__ __forceinline__ float bfhi(u32 u) { return __uint_as_float(u & 0xFFFF0000u); }
__device__ __forceinline__ u16 f2bf(float f) {
  u32 u = __float_as_uint(f);
  u32 r = (u + 0x7FFFu + ((u >> 16) & 1u)) >> 16;
  return (u16)r;
}
__device__ __forceinline__ s8v cvt_row8(const float* __restrict__ p) {
  float4 u = *(const float4*)p;
  float4 v = *(const float4*)(p + 4);
  s8v r;
  r[0] = (short)f2bf(u.x); r[1] = (short)f2bf(u.y);
  r[2] = (short)f2bf(u.z); r[3] = (short)f2bf(u.w);
  r[4] = (short)f2bf(v.x); r[5] = (short)f2bf(v.y);
  r[6] = (short)f2bf(v.z); r[7] = (short)f2bf(v.w);
  return r;
}
__device__ __forceinline__ int colperm(int c) {   // used by skip GEMM
  return (c & ~31) | (((c >> 2) & 3) << 3) | (((c >> 4) & 1) << 2) | (c & 3);
}

// ---------- init: x + bf16 mirrors + zero cnt ----------
__global__ __launch_bounds__(256) void init_x2(const float* __restrict__ emb,
                                               const float* __restrict__ tv,
                                               float* __restrict__ xu,
                                               float* __restrict__ xt,
                                               int* __restrict__ cz,
                                               u16* __restrict__ xbu,
                                               u16* __restrict__ xbt,
                                               int fu, int ft) {
  size_t idx = (size_t)blockIdx.x * 256 + threadIdx.x;
  const size_t nu = (size_t)NUU * DD;
  const size_t nt = (size_t)NTT * DD;
  if (idx < nu) {
    float v = emb[idx];
    xu[idx] = v;
    if (fu) xbu[idx] = f2bf(v);
  } else if (idx < nu + nt) {
    size_t j = idx - nu;
    float v = tv[j & (DD - 1)];
    xt[j] = v;
    if (ft) xbt[j] = f2bf(v);
  } else {
    size_t j = idx - (nu + nt);
    if (j < 300000) cz[j] = 0;
  }
}

// ---------- weights: Wtv fragment-swizzled; combined skip W; zeros ----------
__global__ __launch_bounds__(256) void conv_w(const float* __restrict__ Wq,
                                              const float* __restrict__ Wsk,
                                              const float* __restrict__ bsk,
                                              u16* __restrict__ Wtv,
                                              u16* __restrict__ WtsC,
                                              float* __restrict__ bskC,
                                              float* __restrict__ zeros) {
  int idx = blockIdx.x * 256 + threadIdx.x;
  if (idx < 6 * 65536) {
    int mat = idx >> 16, pos = idx & 65535;
    int e = pos & 7, lane = (pos >> 3) & 63, kk = (pos >> 9) & 3, ct = pos >> 11;
    int col = ct * 16 + (lane & 15);
    int k = kk * 32 + (lane >> 4) * 8 + e;
    Wtv[idx] = f2bf(Wq[((size_t)(mat * 3 + 2) * 128 + k) * 512 + col]);
  }
  if (idx < 4 * 128 * 128) {
    int k = idx & 127, cp = (idx >> 7) & 127, m = idx >> 14;
    int l = m >> 1, isT = m & 1, col = colperm(cp);
    float v;
    if (isT) v = Wsk[((size_t)(l * 3 + 1) * 128 + k) * 128 + col];
    else     v = Wsk[((size_t)(l * 3 + 0) * 128 + k) * 128 + col]
               + Wsk[((size_t)(l * 3 + 2) * 128 + k) * 128 + col];
    WtsC[idx] = f2bf(v);
  }
  if (idx < 4 * 128) {
    int m = idx >> 7, c = idx & 127;
    int l = m >> 1, isT = m & 1;
    bskC[idx] = isT ? bsk[(size_t)(l * 3 + 1) * 128 + c]
                    : bsk[(size_t)(l * 3 + 0) * 128 + c] + bsk[(size_t)(l * 3 + 2) * 128 + c];
  }
  if (idx < 512) zeros[idx] = 0.f;
}

// ---------- M = Wq_h @ Wk_h^T (swizzled output) + U = Wk_h @ bq_h ----------
__global__ __launch_bounds__(256) void mk_m2(const float* __restrict__ Wq_all,
                                             const float* __restrict__ bq_all,
                                             u16* __restrict__ Mwt,
                                             float* __restrict__ Uw) {
  const int rel = blockIdx.x >> 2, h = blockIdx.x & 3;
  const int cpB = blockIdx.y;
  const float* Wq = Wq_all + (size_t)(rel * 3 + 0) * 128 * 512 + h * 128;
  const float* Wk = Wq_all + (size_t)(rel * 3 + 1) * 128 * 512 + h * 128;
  const float* bq = bq_all + (size_t)(rel * 3 + 0) * 512 + h * 128;

  __shared__ float Qs[128][129];
  __shared__ float Ks[16][129];
  for (int idx = threadIdx.x; idx < 16384; idx += 256) {
    int a = idx >> 7, c = idx & 127;
    Qs[a][c] = Wq[(size_t)a * 512 + c];
  }
  for (int idx = threadIdx.x; idx < 2048; idx += 256) {
    int row = idx >> 7, c = idx & 127;
    int d = cpB * 16 + row;
    Ks[row][c] = Wk[(size_t)d * 512 + c];
  }
  __syncthreads();

  const int a = threadIdx.x & 127;
  const int rsel = threadIdx.x >> 7;
  float acc[8] = {};
  for (int c = 0; c < 128; ++c) {
    float qa = Qs[a][c];
    #pragma unroll
    for (int j = 0; j < 8; ++j) acc[j] = fmaf(qa, Ks[rsel * 8 + j][c], acc[j]);
  }
  const int kk = a >> 5, l4a = (a >> 3) & 3, e = a & 7;
  #pragma unroll
  for (int j = 0; j < 8; ++j) {
    int d = cpB * 16 + rsel * 8 + j;
    int col = h * 128 + d;
    int ct = col >> 4, l15c = col & 15;
    int lane = l4a * 16 + l15c;
    Mwt[(size_t)rel * 65536 + ((size_t)(ct * 4 + kk) * 64 + lane) * 8 + e] = f2bf(acc[j]);
  }

  if (cpB == 0 && threadIdx.x < 128) {
    int d = threadIdx.x;
    float s = 0.f;
    for (int c = 0; c < 128; ++c) s = fmaf(Wk[(size_t)d * 512 + c], bq[c], s);
    Uw[((size_t)rel * 4 + h) * 128 + d] = s * 0.08838834764831845f;
  }
}

// ---------- CSR build ----------
__global__ __launch_bounds__(256) void hist3(const int* e0, const int* e1, const int* e2,
                                             int* c0, int* c1, int* c2) {
  int idx = blockIdx.x * 256 + threadIdx.x;
  if (idx >= 3 * EE) return;
  int r = idx / EE, e = idx - r * EE;
  const int* edst = (r == 0 ? e0 : r == 1 ? e1 : e2) + EE;
  int* cnt = r == 0 ? c0 : r == 1 ? c1 : c2;
  atomicAdd(&cnt[edst[e]], 1);
}

__global__ __launch_bounds__(256) void bsum3(const int* c0, const int* c1, const int* c2,
                                             int* __restrict__ bsumA) {
  int b = blockIdx.x;
  int r, lb, n;
  if (b < 196)      { r = 0; lb = b;       n = NUU; }
  else if (b < 587) { r = 1; lb = b - 196; n = NTT; }
  else              { r = 2; lb = b - 587; n = NUU; }
  const int* cnt = r == 0 ? c0 : r == 1 ? c1 : c2;
  int i = lb * 256 + threadIdx.x;
  int v = (i < n) ? cnt[i] : 0;
  #pragma unroll
  for (int o = 1; o < 64; o <<= 1) v += __shfl_xor(v, o);
  __shared__ int ws4[4];
  if ((threadIdx.x & 63) == 0) ws4[threadIdx.x >> 6] = v;
  __syncthreads();
  if (threadIdx.x == 0) bsumA[r * 400 + lb] = ws4[0] + ws4[1] + ws4[2] + ws4[3];
}

__global__ __launch_bounds__(256) void bscan3(int* __restrict__ bsumA) {
  int r = blockIdx.x;
  int* bsum = bsumA + r * 400;
  const int nb = (r == 1) ? 391 : 196;
  __shared__ int sh[256];
  __shared__ int runs;
  if (threadIdx.x == 0) runs = 0;
  __syncthreads();
  for (int base = 0; base < nb; base += 256) {
    int i = base + threadIdx.x;
    int v = (i < nb) ? bsum[i] : 0;
    sh[threadIdx.x] = v;
    __syncthreads();
    for (int o = 1; o < 256; o <<= 1) {
      int t = (threadIdx.x >= o) ? sh[threadIdx.x - o] : 0;
      __syncthreads();
      sh[threadIdx.x] += t;
      __syncthreads();
    }
    int incl = sh[threadIdx.x];
    int r0 = runs;
    if (i < nb) bsum[i] = r0 + incl - v;
    __syncthreads();
    if (threadIdx.x == 0) runs = r0 + sh[255];
    __syncthreads();
  }
}

__global__ __launch_bounds__(256) void rptr3(int* c0, int* c1, int* c2,
                                             const int* __restrict__ bsumA,
                                             int* r0p, int* r1p, int* r2p) {
  int b = blockIdx.x;
  int r, lb, n;
  if (b < 196)      { r = 0; lb = b;       n = NUU; }
  else if (b < 587) { r = 1; lb = b - 196; n = NTT; }
  else              { r = 2; lb = b - 587; n = NUU; }
  int* cnt = r == 0 ? c0 : r == 1 ? c1 : c2;
  int* rptr = r == 0 ? r0p : r == 1 ? r1p : r2p;
  __shared__ int sh[256];
  int i = lb * 256 + threadIdx.x;
  int v = (i < n) ? cnt[i] : 0;
  sh[threadIdx.x] = v;
  __syncthreads();
  for (int o = 1; o < 256; o <<= 1) {
    int t = (threadIdx.x >= o) ? sh[threadIdx.x - o] : 0;
    __syncthreads();
    sh[threadIdx.x] += t;
    __syncthreads();
  }
  int excl = sh[threadIdx.x] - v + bsumA[r * 400 + lb];
  if (i < n) { rptr[i] = excl; cnt[i] = excl; }
  if (i == 0) rptr[n] = EE;
}

__global__ __launch_bounds__(256) void fill3(const int* e0, const int* e1, const int* e2,
                                             int* c0, int* c1, int* c2,
                                             int* s0, int* s1, int* s2) {
  int idx = blockIdx.x * 256 + threadIdx.x;
  if (idx >= 3 * EE) return;
  int r = idx / EE, e = idx - r * EE;
  const int* ebase = (r == 0 ? e0 : r == 1 ? e1 : e2);
  int* cursor = r == 0 ? c0 : r == 1 ? c1 : c2;
  int* csrc = r == 0 ? s0 : r == 1 ? s1 : s2;
  int pos = atomicAdd(&cursor[ebase[EE + e]], 1);
  csrc[pos] = ebase[e];
}

// ---------- LDS-staged q'/V GEMM: 32 rows x 512 cols per block ----------
// V branch optionally fuses c[s][h] = sum_d x_s[d] * cU[h*128+d]  (cOut != null)
struct GRel3 {
  const u16* Xqb; const float* Xqf;
  const u16* Xvb; const float* Xvf;
  const u16* Wq; const u16* Wv;
  const float* bzq; const float* bzv;
  const float* cU; float* cOut;
  u16 *oq, *ov;
  int nq, nv, bq, bv, xbq, xbv;
};

__global__ __launch_bounds__(256) void gemm_rel3(GRel3 a) {
  __shared__ u16 Xs[32 * 128];
  __shared__ u16 Os[32 * 512];
  const int bx = blockIdx.x;
  int lb, n, usexb, isV;
  const u16* Xb; const float* Xf; const u16* Wsw; const float* bias; u16* Y;
  if (bx < a.bq) {
    lb = bx; n = a.nq; Xb = a.Xqb; Xf = a.Xqf; Wsw = a.Wq; bias = a.bzq; Y = a.oq;
    usexb = a.xbq; isV = 0;
  } else {
    lb = bx - a.bq; n = a.nv; Xb = a.Xvb; Xf = a.Xvf; Wsw = a.Wv; bias = a.bzv; Y = a.ov;
    usexb = a.xbv; isV = 1;
  }
  const int row0 = lb * 32;
  if (row0 >= n) return;
  const int tid = threadIdx.x;

  if (usexb) {
    #pragma unroll
    for (int q = 0; q < 2; ++q) {
      int c = tid + q * 256;
      int row = c >> 4, off = (c & 15) * 16;
      int gr = row0 + row; if (gr >= n) gr = n - 1;
      uint4 val = *(const uint4*)((const char*)Xb + (size_t)gr * 256 + off);
      *(uint4*)((char*)Xs + row * 256 + (off ^ ((row & 7) << 4))) = val;
    }
  } else {
    #pragma unroll
    for (int q = 0; q < 4; ++q) {
      int c = tid + q * 256;
      int row = c >> 5, sub = c & 31;
      int gr = row0 + row; if (gr >= n) gr = n - 1;
      float4 f = *(const float4*)(Xf + (size_t)gr * 128 + sub * 4);
      ushort4 pk;
      pk.x = f2bf(f.x); pk.y = f2bf(f.y); pk.z = f2bf(f.z); pk.w = f2bf(f.w);
      *(ushort4*)((char*)Xs + row * 256 + ((sub * 8) ^ ((row & 7) << 4))) = pk;
    }
  }
  __syncthreads();

  // ---- fused c for V blocks: 8 threads per row, vectorized b128 LDS reads ----
  if (isV && a.cOut != nullptr) {
    const int row = tid >> 3, k = tid & 7;
    const int gr = row0 + row;
    const int swz = (row & 7) << 4;
    uint4 ca = *(const uint4*)((const char*)Xs + row * 256 + ((32 * k) ^ swz));
    uint4 cb = *(const uint4*)((const char*)Xs + row * 256 + ((32 * k + 16) ^ swz));
    u32 words[8] = {ca.x, ca.y, ca.z, ca.w, cb.x, cb.y, cb.z, cb.w};
    float part[4] = {};
    #pragma unroll
    for (int wi = 0; wi < 8; ++wi) {
      int d = k * 16 + wi * 2;
      float x0 = bflo(words[wi]);
      float x1 = bfhi(words[wi]);
      #pragma unroll
      for (int h = 0; h < 4; ++h) {
        part[h] = fmaf(x0, a.cU[h * 128 + d], part[h]);
        part[h] = fmaf(x1, a.cU[h * 128 + d + 1], part[h]);
      }
    }
    #pragma unroll
    for (int h = 0; h < 4; ++h) {
      #pragma unroll
      for (int o = 1; o < 8; o <<= 1) part[h] += __shfl_xor(part[h], o);
    }
    if (k == 0 && gr < n) {
      *(float4*)(a.cOut + (size_t)gr * 4) = make_float4(part[0], part[1], part[2], part[3]);
    }
  }

  const int wid = tid >> 6, lane = tid & 63;
  const int l15 = lane & 15, l4 = lane >> 4;

  s8v afr[2][4];
  #pragma unroll
  for (int rt = 0; rt < 2; ++rt) {
    int row = rt * 16 + l15;
    #pragma unroll
    for (int kk = 0; kk < 4; ++kk)
      afr[rt][kk] = *(const s8v*)((const char*)Xs + row * 256 + ((kk * 64 + l4 * 16) ^ ((row & 7) << 4)));
  }

  const u16* wbase = Wsw + ((size_t)wid * 16384) + (size_t)lane * 8;
  s8v w0[4], w1[4];
  #pragma unroll
  for (int kk = 0; kk < 4; ++kk) w0[kk] = *(const s8v*)(wbase + kk * 512);

  #pragma unroll
  for (int ctl = 0; ctl < 8; ++ctl) {
    const s8v* cw = (ctl & 1) ? w1 : w0;
    s8v* nw = (ctl & 1) ? w0 : w1;
    if (ctl + 1 < 8) {
      #pragma unroll
      for (int kk = 0; kk < 4; ++kk)
        nw[kk] = *(const s8v*)(wbase + (ctl + 1) * 2048 + kk * 512);
    }
    f4v acc0 = {}, acc1 = {};
    #pragma unroll
    for (int kk = 0; kk < 4; ++kk) {
      acc0 = __builtin_amdgcn_mfma_f32_16x16x32_bf16(cw[kk], afr[0][kk], acc0, 0, 0, 0);
      acc1 = __builtin_amdgcn_mfma_f32_16x16x32_bf16(cw[kk], afr[1][kk], acc1, 0, 0, 0);
    }
    const int colb = wid * 128 + ctl * 16 + l4 * 4;
    const float4 bb = *(const float4*)(bias + colb);
    {
      int row = l15;
      ushort4 pk;
      pk.x = f2bf(acc0[0] + bb.x); pk.y = f2bf(acc0[1] + bb.y);
      pk.z = f2bf(acc0[2] + bb.z); pk.w = f2bf(acc0[3] + bb.w);
      *(ushort4*)((char*)Os + row * 1024 + ((colb * 2) ^ ((row & 7) << 4))) = pk;
    }
    {
      int row = 16 + l15;
      ushort4 pk;
      pk.x = f2bf(acc1[0] + bb.x); pk.y = f2bf(acc1[1] + bb.y);
      pk.z = f2bf(acc1[2] + bb.z); pk.w = f2bf(acc1[3] + bb.w);
      *(ushort4*)((char*)Os + row * 1024 + ((colb * 2) ^ ((row & 7) << 4))) = pk;
    }
  }
  __syncthreads();

  #pragma unroll
  for (int r = 0; r < 8; ++r) {
    int row = wid * 8 + r;
    int gr = row0 + row;
    if (gr < n) {
      uint4 val = *(const uint4*)((const char*)Os + row * 1024 + ((lane * 16) ^ ((row & 7) << 4)));
      *(uint4*)(Y + (size_t)gr * 512 + lane * 8) = val;
    }
  }
}

// ---------- skip GEMM (flat grid, STORE) ----------
__global__ __launch_bounds__(256) void gemm_skip3(const u16* xbu, const u16* xbt,
                                                  const float* xfu, const float* xft,
                                                  const u16* Wu, const u16* Wtw,
                                                  const float* bu, const float* btw,
                                                  float* aggu, float* aggt,
                                                  int fu, int ft) {
  const int bx = blockIdx.x;
  int job, lb;
  if (bx < BU) { job = 0; lb = bx; } else { job = 1; lb = bx - BU; }
  const int n = job ? NTT : NUU;
  const int bm = lb * 128;
  const u16* XB = job ? xbt : xbu;
  const float* XF = job ? xft : xfu;
  const u16* Wt = job ? Wtw : Wu;
  const float* bias = job ? btw : bu;
  float* out = job ? aggt : aggu;
  const int usexb = job ? ft : fu;

  const int wid = threadIdx.x >> 6, lane = threadIdx.x & 63;
  const int l15 = lane & 15, l4 = lane >> 4;
  const int rbase = bm + wid * 32;
  int r0 = rbase + l15;      if (r0 >= n) r0 = n - 1;
  int r1 = rbase + 16 + l15; if (r1 >= n) r1 = n - 1;
  s8v a0[4], a1[4];
  if (usexb) {
    const u16* xb0 = XB + (size_t)r0 * DD + l4 * 8;
    const u16* xb1 = XB + (size_t)r1 * DD + l4 * 8;
    #pragma unroll
    for (int kk = 0; kk < 4; ++kk) {
      a0[kk] = *(const s8v*)(xb0 + kk * 32);
      a1[kk] = *(const s8v*)(xb1 + kk * 32);
    }
  } else {
    const float* xp0 = XF + (size_t)r0 * DD + l4 * 8;
    const float* xp1 = XF + (size_t)r1 * DD + l4 * 8;
    #pragma unroll
    for (int kk = 0; kk < 4; ++kk) {
      a0[kk] = cvt_row8(xp0 + kk * 32);
      a1[kk] = cvt_row8(xp1 + kk * 32);
    }
  }

  const u16* wp = Wt + (size_t)l15 * DD + l4 * 8;
  const bool ok0 = (rbase + l15 < n), ok1 = (rbase + 16 + l15 < n);
  float* yp0 = out + (size_t)(rbase + l15) * DD + l4 * 8;
  float* yp1 = out + (size_t)(rbase + 16 + l15) * DD + l4 * 8;

  s8v w0[8], w1[8];
  #pragma unroll
  for (int kk = 0; kk < 4; ++kk) {
    w0[kk]     = *(const s8v*)(wp + kk * 32);
    w0[4 + kk] = *(const s8v*)(wp + 16 * DD + kk * 32);
  }
  #pragma unroll
  for (int p = 0; p < 4; ++p) {
    const s8v* cw = (p & 1) ? w1 : w0;
    s8v* nw = (p & 1) ? w0 : w1;
    if (p + 1 < 4) {
      const u16* wq = wp + (size_t)(2 * (p + 1)) * 16 * DD;
      #pragma unroll
      for (int kk = 0; kk < 4; ++kk) {
        nw[kk]     = *(const s8v*)(wq + kk * 32);
        nw[4 + kk] = *(const s8v*)(wq + 16 * DD + kk * 32);
      }
    }
    f4v aE0 = {}, aE1 = {}, aO0 = {}, aO1 = {};
    #pragma unroll
    for (int kk = 0; kk < 4; ++kk) {
      aE0 = __builtin_amdgcn_mfma_f32_16x16x32_bf16(cw[kk], a0[kk], aE0, 0, 0, 0);
      aE1 = __builtin_amdgcn_mfma_f32_16x16x32_bf16(cw[kk], a1[kk], aE1, 0, 0, 0);
      aO0 = __builtin_amdgcn_mfma_f32_16x16x32_bf16(cw[4 + kk], a0[kk], aO0, 0, 0, 0);
      aO1 = __builtin_amdgcn_mfma_f32_16x16x32_bf16(cw[4 + kk], a1[kk], aO1, 0, 0, 0);
    }
    const float4 bbE = *(const float4*)(bias + p * 32 + l4 * 8);
    const float4 bbO = *(const float4*)(bias + p * 32 + l4 * 8 + 4);
    if (ok0) {
      *(float4*)(yp0 + p * 32) = make_float4(aE0[0] + bbE.x, aE0[1] + bbE.y, aE0[2] + bbE.z, aE0[3] + bbE.w);
      *(float4*)(yp0 + p * 32 + 4) = make_float4(aO0[0] + bbO.x, aO0[1] + bbO.y, aO0[2] + bbO.z, aO0[3] + bbO.w);
    }
    if (ok1) {
      *(float4*)(yp1 + p * 32) = make_float4(aE1[0] + bbE.x, aE1[1] + bbE.y, aE1[2] + bbE.z, aE1[3] + bbE.w);
      *(float4*)(yp1 + p * 32 + 4) = make_float4(aO1[0] + bbO.x, aO1[1] + bbO.y, aO1[2] + bbO.z, aO1[3] + bbO.w);
    }
  }
}

// ---------- edge kernel: logits via q'.x_s + c(s); V gather; deg-1 fast path ----------
template<int XF>
__global__ __launch_bounds__(256) void edge_fused2(const u16* __restrict__ qp,
                                                   const u16* __restrict__ v,
                                                   const u16* __restrict__ xsb,
                                                   const float* __restrict__ xsf,
                                                   const float* __restrict__ cbuf,
                                                   const int* __restrict__ rptr,
                                                   const int* __restrict__ csrc,
                                                   float* __restrict__ agg,
                                                   int nd, int qs32) {
  int node = (int)(((size_t)blockIdx.x * 256 + threadIdx.x) >> 6);
  int lane = threadIdx.x & 63;
  if (node >= nd) return;
  int e0 = rptr[node], e1 = rptr[node + 1];
  if (e0 == e1) return;
  const int g = lane >> 4, i = lane & 15;
  float acc[8];

  if (e1 - e0 == 1) {
    int s = csrc[e0];
    const u32* vp = (const u32*)v + (size_t)s * 256 + lane * 4;
    #pragma unroll
    for (int j = 0; j < 4; ++j) { u32 u = vp[j]; acc[2 * j] = bflo(u); acc[2 * j + 1] = bfhi(u); }
  } else {
    u32 qv[4];
    {
      const u32* qq = (const u32*)qp + (size_t)node * qs32 + g * 64 + i * 4;
      #pragma unroll
      for (int j = 0; j < 4; ++j) qv[j] = qq[j];
    }
    float m = -1e30f, z = 0.f;
    #pragma unroll
    for (int j = 0; j < 8; ++j) acc[j] = 0.f;

    int s_cur = csrc[e0];
    u32 xc[4]; float xf[8];
    if (XF) {
      const u32* xp = (const u32*)xsb + (size_t)s_cur * 64 + i * 4;
      #pragma unroll
      for (int j = 0; j < 4; ++j) xc[j] = xp[j];
    } else {
      const float* xp = xsf + (size_t)s_cur * 128 + i * 8;
      #pragma unroll
      for (int j = 0; j < 8; ++j) xf[j] = xp[j];
    }

    for (int e = e0; e < e1; ++e) {
      u32 vcur[4];
      {
        const u32* vp = (const u32*)v + (size_t)s_cur * 256 + lane * 4;
        #pragma unroll
        for (int j = 0; j < 4; ++j) vcur[j] = vp[j];
      }
      float cs = cbuf[(size_t)s_cur * 4 + g];
      const bool has = (e + 1 < e1);
      int s_nxt = csrc[has ? e + 1 : e0];
      u32 xn[4]; float xnf[8];
      if (XF) {
        const u32* xp = (const u32*)xsb + (size_t)s_nxt * 64 + i * 4;
        #pragma unroll
        for (int j = 0; j < 4; ++j) xn[j] = xp[j];
      } else {
        const float* xp = xsf + (size_t)s_nxt * 128 + i * 8;
        #pragma unroll
        for (int j = 0; j < 8; ++j) xnf[j] = xp[j];
      }

      float dot = 0.f;
      if (XF) {
        #pragma unroll
        for (int j = 0; j < 4; ++j)
          dot += bflo(qv[j]) * bflo(xc[j]) + bfhi(qv[j]) * bfhi(xc[j]);
      } else {
        #pragma unroll
        for (int j = 0; j < 4; ++j)
          dot += bflo(qv[j]) * xf[2 * j] + bfhi(qv[j]) * xf[2 * j + 1];
      }
      dot += __shfl_xor(dot, 1);
      dot += __shfl_xor(dot, 2);
      dot += __shfl_xor(dot, 4);
      dot += __shfl_xor(dot, 8);
      float lg = dot * 0.08838834764831845f + cs;
      float w;
      if (lg > m) {
        float sc = __expf(m - lg);
        z *= sc;
        #pragma unroll
        for (int j = 0; j < 8; ++j) acc[j] *= sc;
        m = lg; w = 1.f;
      } else {
        w = __expf(lg - m);
      }
      z += w;
      #pragma unroll
      for (int j = 0; j < 4; ++j) {
        acc[2 * j]     += w * bflo(vcur[j]);
        acc[2 * j + 1] += w * bfhi(vcur[j]);
      }
      if (has) {
        s_cur = s_nxt;
        if (XF) {
          #pragma unroll
          for (int j = 0; j < 4; ++j) xc[j] = xn[j];
        } else {
          #pragma unroll
          for (int j = 0; j < 8; ++j) xf[j] = xnf[j];
        }
      }
    }
    float iz = 1.f / z;
    #pragma unroll
    for (int j = 0; j < 8; ++j) acc[j] *= iz;
  }

  #pragma unroll
  for (int j = 0; j < 8; ++j) acc[j] *= 0.25f;
  #pragma unroll
  for (int o = 16; o < 64; o <<= 1) {
    #pragma unroll
    for (int j = 0; j < 8; ++j) acc[j] += __shfl_xor(acc[j], o);
  }
  if (lane < 16) {
    float* op = agg + (size_t)node * DD + lane * 8;
    #pragma unroll
    for (int j = 0; j < 8; ++j) op[j] += acc[j];
  }
}

// ---------- l0-tu shortcut: uniform softmax over broadcast K/V ----------
__global__ __launch_bounds__(256) void add_bcast4(const u16* __restrict__ v,
                                                  const int* __restrict__ rptr,
                                                  float* __restrict__ agg, int nd) {
  int node = (int)(((size_t)blockIdx.x * 256 + threadIdx.x) >> 6);
  int lane = threadIdx.x & 63;
  if (node >= nd) return;
  if (rptr[node + 1] <= rptr[node]) return;
  const u32* vp = (const u32*)v;   // row 0
  float a0 = 0.f, a1 = 0.f;
  #pragma unroll
  for (int h = 0; h < 4; ++h) {
    u32 u = vp[h * 64 + lane];
    a0 += bflo(u); a1 += bfhi(u);
  }
  float* op = agg + (size_t)node * DD + 2 * lane;
  op[0] += 0.25f * a0;
  op[1] += 0.25f * a1;
}

// ---------- LayerNorm + residual (+ bf16 mirror writes), vectorized ----------
__global__ __launch_bounds__(256) void ln2(const float* __restrict__ aggu,
                                           const float* __restrict__ aggt,
                                           const float* __restrict__ g2,
                                           const float* __restrict__ b2,
                                           float* __restrict__ xu,
                                           float* __restrict__ xt,
                                           u16* __restrict__ xbu,
                                           u16* __restrict__ xbt,
                                           int wbu, int wbt) {
  int wid = (int)(((size_t)blockIdx.x * 256 + threadIdx.x) >> 6);
  int lane = threadIdx.x & 63;
  if (wid >= NUU + NTT) return;
  const float* ap; float* xp; const float* g; const float* b; u16* xbp; int wb;
  if (wid < NUU) {
    ap = aggu + (size_t)wid * DD; xp = xu + (size_t)wid * DD;
    xbp = xbu ? xbu + (size_t)wid * DD : nullptr; g = g2; b = b2; wb = wbu;
  } else {
    int t = wid - NUU;
    ap = aggt + (size_t)t * DD; xp = xt + (size_t)t * DD;
    xbp = xbt ? xbt + (size_t)t * DD : nullptr; g = g2 + DD; b = b2 + DD; wb = wbt;
  }
  float2 va = *(const float2*)(ap + 2 * lane);
  float v0 = va.x, v1 = va.y;
  float s = v0 + v1;
  #pragma unroll
  for (int o = 1; o < 64; o <<= 1) s += __shfl_xor(s, o);
  float mean = s * (1.0f / DD);
  float d0 = v0 - mean, d1 = v1 - mean;
  float sq = d0 * d0 + d1 * d1;
  #pragma unroll
  for (int o = 1; o < 64; o <<= 1) sq += __shfl_xor(sq, o);
  float rstd = rsqrtf(sq * (1.0f / DD) + 1e-5f);
  float2 xv = *(const float2*)(xp + 2 * lane);
  float2 gv = *(const float2*)(g + 2 * lane);
  float2 bv = *(const float2*)(b + 2 * lane);
  float n0 = gv.x * d0 * rstd + bv.x + xv.x;
  float n1 = gv.y * d1 * rstd + bv.y + xv.y;
  *(float2*)(xp + 2 * lane) = make_float2(n0, n1);
  if (wb) {
    *(u32*)(xbp + 2 * lane) = (u32)f2bf(n0) | ((u32)f2bf(n1) << 16);
  }
}

extern "C" void kernel_launch(void* const* d_in, const int* in_sizes, int n_in,
                              void* d_out, int out_size, void* d_ws, size_t ws_size,
                              hipStream_t stream) {
  const float* emb_user = (const float*)d_in[0];
  const float* tv_tweet = (const float*)d_in[1];
  const float* W_qkv  = (const float*)d_in[2];
  const float* b_qkv  = (const float*)d_in[3];
  const float* W_skip = (const float*)d_in[4];
  const float* b_skip = (const float*)d_in[5];
  const float* ln_g   = (const float*)d_in[6];
  const float* ln_b   = (const float*)d_in[7];
  const int* edges[3] = { (const int*)d_in[8], (const int*)d_in[9], (const int*)d_in[10] };

  float* x_user  = (float*)d_out;
  float* x_tweet = x_user + (size_t)NUU * DD;

  // ---- workspace layout (identical to R12/R14) ----
  const size_t fixed = 786432 + 131072 + 2048 + 786432 + 12288 + 2048 + 1600000
                     + 76800000 + (size_t)3 * 400032 + (size_t)3 * 400000 + 4800
                     + 153600000 + 4096;
  int XBU = 0, XBT = 0;
  if      (ws_size >= fixed + 38400000) { XBU = 1; XBT = 1; }
  else if (ws_size >= fixed + 25600000) { XBT = 1; }

  char* w = (char*)d_ws;
  u16* Wtv = (u16*)w;        w += 786432;
  u16* WtsC = (u16*)w;       w += 131072;
  float* bskC = (float*)w;   w += 2048;
  u16* Mwt = (u16*)w;        w += 786432;
  float* Uw = (float*)w;     w += 12288;
  float* zeros = (float*)w;  w += 2048;
  float* cbuf = (float*)w;   w += 1600000;
  float* agg_u = (float*)w;  w += (size_t)NUU * DD * 4;
  float* agg_t = (float*)w;  w += (size_t)NTT * DD * 4;
  int* rptrA[3]; int* csrcA[3];
  for (int r = 0; r < 3; ++r) { rptrA[r] = (int*)w; w += 400032; }
  for (int r = 0; r < 3; ++r) { csrcA[r] = (int*)w; w += 400000; }
  int* bsumA = (int*)w;      w += 4800;
  u16* xb_user = nullptr; u16* xb_tweet = nullptr;
  if (XBT) { xb_tweet = (u16*)w; w += (size_t)NTT * DD * 2; }
  if (XBU) { xb_user = (u16*)w;  w += (size_t)NUU * DD * 2; }
  u16* arena = (u16*)w;
  int* cntA[3];
  cntA[0] = (int*)arena; cntA[1] = cntA[0] + 100000; cntA[2] = cntA[0] + 200000;

  init_x2<<<(19500000 + 255) / 256, 256, 0, stream>>>(emb_user, tv_tweet, x_user, x_tweet,
                                                      cntA[0], xb_user, xb_tweet, XBU, XBT);
  conv_w<<<(6 * 65536 + 255) / 256, 256, 0, stream>>>(W_qkv, W_skip, b_skip,
                                                      Wtv, WtsC, bskC, zeros);
  mk_m2<<<dim3(24, 8), 256, 0, stream>>>(W_qkv, b_qkv, Mwt, Uw);

  hist3<<<(3 * EE + 255) / 256, 256, 0, stream>>>(edges[0], edges[1], edges[2],
                                                  cntA[0], cntA[1], cntA[2]);
  bsum3<<<783, 256, 0, stream>>>(cntA[0], cntA[1], cntA[2], bsumA);
  bscan3<<<3, 256, 0, stream>>>(bsumA);
  rptr3<<<783, 256, 0, stream>>>(cntA[0], cntA[1], cntA[2], bsumA, rptrA[0], rptrA[1], rptrA[2]);
  fill3<<<(3 * EE + 255) / 256, 256, 0, stream>>>(edges[0], edges[1], edges[2],
                                                  cntA[0], cntA[1], cntA[2],
                                                  csrcA[0], csrcA[1], csrcA[2]);

  const int stt[3] = {0, 0, 1}, dtt[3] = {0, 1, 0};
  const int cnt2[2] = {NUU, NTT};
  float* xs[2]   = {x_user, x_tweet};
  u16* xbs[2]    = {xb_user, xb_tweet};
  const int xbf[2] = {XBU, XBT};
  float* aggs[2] = {agg_u, agg_t};

  for (int l = 0; l < 2; ++l) {
    gemm_skip3<<<BU + BT, 256, 0, stream>>>(
        xb_user, xb_tweet, x_user, x_tweet,
        WtsC + (size_t)(2 * l) * 128 * 128, WtsC + (size_t)(2 * l + 1) * 128 * 128,
        bskC + (size_t)(2 * l) * 128, bskC + (size_t)(2 * l + 1) * 128,
        agg_u, agg_t, XBU, XBT);

    for (int r = 0; r < 3; ++r) {
      const int st = stt[r], dt = dtt[r];
      const int ns = cnt2[st], nd = cnt2[dt];
      const int rel = l * 3 + r;
      const bool qDeg = (l == 0 && dt == 1);   // ut-l0: broadcast dst
      const bool uniSM = (l == 0 && st == 1);  // tu-l0: broadcast src -> uniform softmax

      const int nq_eff = uniSM ? 0 : (qDeg ? 1 : nd);
      const int nv_eff = uniSM ? 1 : ns;
      u16* qb_r = arena;
      u16* vb_r = arena + (size_t)nq_eff * HCC;

      GRel3 ga;
      ga.Xqb = xbs[dt]; ga.Xqf = xs[dt]; ga.xbq = xbf[dt];
      ga.Xvb = xbs[st]; ga.Xvf = xs[st]; ga.xbv = xbf[st];
      ga.Wq = Mwt + (size_t)rel * 65536;
      ga.Wv = Wtv + (size_t)rel * 65536;
      ga.bzq = zeros;
      ga.bzv = b_qkv + (size_t)(rel * 3 + 2) * HCC;
      ga.cU = Uw + (size_t)rel * 512;
      ga.cOut = uniSM ? nullptr : cbuf;
      ga.oq = qb_r; ga.ov = vb_r;
      ga.nq = nq_eff; ga.nv = nv_eff;
      ga.bq = (nq_eff + 31) / 32; ga.bv = (nv_eff + 31) / 32;
      gemm_rel3<<<ga.bq + ga.bv, 256, 0, stream>>>(ga);

      const int eblk = (nd + 3) / 4;
      if (uniSM) {
        add_bcast4<<<eblk, 256, 0, stream>>>(vb_r, rptrA[r], aggs[dt], nd);
      } else {
        const int qs32 = qDeg ? 0 : 256;
        if (xbf[st])
          edge_fused2<1><<<eblk, 256, 0, stream>>>(qb_r, vb_r, xbs[st], xs[st], cbuf,
                                                   rptrA[r], csrcA[r], aggs[dt], nd, qs32);
        else
          edge_fused2<0><<<eblk, 256, 0, stream>>>(qb_r, vb_r, xbs[st], xs[st], cbuf,
                                                   rptrA[r], csrcA[r], aggs[dt], nd, qs32);
      }
    }
    ln2<<<(NUU + NTT + 3) / 4, 256, 0, stream>>>(agg_u, agg_t,
                                                 ln_g + (size_t)l * 2 * DD,
                                                 ln_b + (size_t)l * 2 * DD,
                                                 x_user, x_tweet,
                                                 xb_user, xb_tweet,
                                                 XBU && l == 0, XBT && l == 0);
  }
}

// Round 16
// 662.427 us; speedup vs baseline: 1.0027x; 1.0027x over previous
//
#include <hip/hip_runtime.h>
#include <hip/hip_bf16.h>
#include <math.h>

typedef unsigned short u16;
typedef unsigned int   u32;
typedef __attribute__((ext_vector_type(8))) short s8v;    // 8 x bf16
typedef __attribute__((ext_vector_type(8))) unsigned short u16x8;
typedef __attribute__((ext_vector_type(4))) float f4v;    // MFMA accumulator

#define NUU 50000
#define NTT 100000
#define EE  100000
#define DD  128
#define HH  4
#define HCC 512
#define BU  391
#define BT  782

// ---------- helpers ----------
__device__ __forceinline__ float bflo(u32 u) { return __uint_as_float(u << 16); }
__device__ __forceinline__ float bfhi(u32 u) { return __uint_as_float(u & 0xFFFF0000u); }
__device__ __forceinline__ u16 f2bf(float f) {
  u32 u = __float_as_uint(f);
  u32 r = (u + 0x7FFFu + ((u >> 16) & 1u)) >> 16;
  return (u16)r;
}
__device__ __forceinline__ s8v cvt_row8(const float* __restrict__ p) {
  float4 u = *(const float4*)p;
  float4 v = *(const float4*)(p + 4);
  s8v r;
  r[0] = (short)f2bf(u.x); r[1] = (short)f2bf(u.y);
  r[2] = (short)f2bf(u.z); r[3] = (short)f2bf(u.w);
  r[4] = (short)f2bf(v.x); r[5] = (short)f2bf(v.y);
  r[6] = (short)f2bf(v.z); r[7] = (short)f2bf(v.w);
  return r;
}
__device__ __forceinline__ int colperm(int c) {   // used by skip GEMM
  return (c & ~31) | (((c >> 2) & 3) << 3) | (((c >> 4) & 1) << 2) | (c & 3);
}

// ---------- init: mirrors (or f32 x in fallback) + zero cnt ----------
__global__ __launch_bounds__(256) void init_x2(const float* __restrict__ emb,
                                               const float* __restrict__ tv,
                                               float* __restrict__ xu,
                                               float* __restrict__ xt,
                                               int* __restrict__ cz,
                                               u16* __restrict__ xbu,
                                               u16* __restrict__ xbt,
                                               int fu, int ft) {
  size_t idx = (size_t)blockIdx.x * 256 + threadIdx.x;
  const size_t nu = (size_t)NUU * DD;
  const size_t nt = (size_t)NTT * DD;
  if (idx < nu) {
    float v = emb[idx];
    if (fu) xbu[idx] = f2bf(v);   // mirror path: f32 x first written by ln2-l0
    else    xu[idx] = v;
  } else if (idx < nu + nt) {
    size_t j = idx - nu;
    float v = tv[j & (DD - 1)];
    if (ft) xbt[j] = f2bf(v);
    else    xt[j] = v;
  } else {
    size_t j = idx - (nu + nt);
    if (j < 300000) cz[j] = 0;
  }
}

// ---------- weights: Wtv fragment-swizzled; combined skip W; zeros ----------
__global__ __launch_bounds__(256) void conv_w(const float* __restrict__ Wq,
                                              const float* __restrict__ Wsk,
                                              const float* __restrict__ bsk,
                                              u16* __restrict__ Wtv,
                                              u16* __restrict__ WtsC,
                                              float* __restrict__ bskC,
                                              float* __restrict__ zeros) {
  int idx = blockIdx.x * 256 + threadIdx.x;
  if (idx < 6 * 65536) {
    int mat = idx >> 16, pos = idx & 65535;
    int e = pos & 7, lane = (pos >> 3) & 63, kk = (pos >> 9) & 3, ct = pos >> 11;
    int col = ct * 16 + (lane & 15);
    int k = kk * 32 + (lane >> 4) * 8 + e;
    Wtv[idx] = f2bf(Wq[((size_t)(mat * 3 + 2) * 128 + k) * 512 + col]);
  }
  if (idx < 4 * 128 * 128) {
    int k = idx & 127, cp = (idx >> 7) & 127, m = idx >> 14;
    int l = m >> 1, isT = m & 1, col = colperm(cp);
    float v;
    if (isT) v = Wsk[((size_t)(l * 3 + 1) * 128 + k) * 128 + col];
    else     v = Wsk[((size_t)(l * 3 + 0) * 128 + k) * 128 + col]
               + Wsk[((size_t)(l * 3 + 2) * 128 + k) * 128 + col];
    WtsC[idx] = f2bf(v);
  }
  if (idx < 4 * 128) {
    int m = idx >> 7, c = idx & 127;
    int l = m >> 1, isT = m & 1;
    bskC[idx] = isT ? bsk[(size_t)(l * 3 + 1) * 128 + c]
                    : bsk[(size_t)(l * 3 + 0) * 128 + c] + bsk[(size_t)(l * 3 + 2) * 128 + c];
  }
  if (idx < 512) zeros[idx] = 0.f;
}

// ---------- M = Wq_h @ Wk_h^T (swizzled output) + U = Wk_h @ bq_h ----------
__global__ __launch_bounds__(256) void mk_m2(const float* __restrict__ Wq_all,
                                             const float* __restrict__ bq_all,
                                             u16* __restrict__ Mwt,
                                             float* __restrict__ Uw) {
  const int rel = blockIdx.x >> 2, h = blockIdx.x & 3;
  const int cpB = blockIdx.y;
  const float* Wq = Wq_all + (size_t)(rel * 3 + 0) * 128 * 512 + h * 128;
  const float* Wk = Wq_all + (size_t)(rel * 3 + 1) * 128 * 512 + h * 128;
  const float* bq = bq_all + (size_t)(rel * 3 + 0) * 512 + h * 128;

  __shared__ float Qs[128][129];
  __shared__ float Ks[16][129];
  for (int idx = threadIdx.x; idx < 16384; idx += 256) {
    int a = idx >> 7, c = idx & 127;
    Qs[a][c] = Wq[(size_t)a * 512 + c];
  }
  for (int idx = threadIdx.x; idx < 2048; idx += 256) {
    int row = idx >> 7, c = idx & 127;
    int d = cpB * 16 + row;
    Ks[row][c] = Wk[(size_t)d * 512 + c];
  }
  __syncthreads();

  const int a = threadIdx.x & 127;
  const int rsel = threadIdx.x >> 7;
  float acc[8] = {};
  for (int c = 0; c < 128; ++c) {
    float qa = Qs[a][c];
    #pragma unroll
    for (int j = 0; j < 8; ++j) acc[j] = fmaf(qa, Ks[rsel * 8 + j][c], acc[j]);
  }
  const int kk = a >> 5, l4a = (a >> 3) & 3, e = a & 7;
  #pragma unroll
  for (int j = 0; j < 8; ++j) {
    int d = cpB * 16 + rsel * 8 + j;
    int col = h * 128 + d;
    int ct = col >> 4, l15c = col & 15;
    int lane = l4a * 16 + l15c;
    Mwt[(size_t)rel * 65536 + ((size_t)(ct * 4 + kk) * 64 + lane) * 8 + e] = f2bf(acc[j]);
  }

  if (cpB == 0 && threadIdx.x < 128) {
    int d = threadIdx.x;
    float s = 0.f;
    for (int c = 0; c < 128; ++c) s = fmaf(Wk[(size_t)d * 512 + c], bq[c], s);
    Uw[((size_t)rel * 4 + h) * 128 + d] = s * 0.08838834764831845f;
  }
}

// ---------- CSR build ----------
__global__ __launch_bounds__(256) void hist3(const int* e0, const int* e1, const int* e2,
                                             int* c0, int* c1, int* c2) {
  int idx = blockIdx.x * 256 + threadIdx.x;
  if (idx >= 3 * EE) return;
  int r = idx / EE, e = idx - r * EE;
  const int* edst = (r == 0 ? e0 : r == 1 ? e1 : e2) + EE;
  int* cnt = r == 0 ? c0 : r == 1 ? c1 : c2;
  atomicAdd(&cnt[edst[e]], 1);
}

__global__ __launch_bounds__(256) void bsum3(const int* c0, const int* c1, const int* c2,
                                             int* __restrict__ bsumA) {
  int b = blockIdx.x;
  int r, lb, n;
  if (b < 196)      { r = 0; lb = b;       n = NUU; }
  else if (b < 587) { r = 1; lb = b - 196; n = NTT; }
  else              { r = 2; lb = b - 587; n = NUU; }
  const int* cnt = r == 0 ? c0 : r == 1 ? c1 : c2;
  int i = lb * 256 + threadIdx.x;
  int v = (i < n) ? cnt[i] : 0;
  #pragma unroll
  for (int o = 1; o < 64; o <<= 1) v += __shfl_xor(v, o);
  __shared__ int ws4[4];
  if ((threadIdx.x & 63) == 0) ws4[threadIdx.x >> 6] = v;
  __syncthreads();
  if (threadIdx.x == 0) bsumA[r * 400 + lb] = ws4[0] + ws4[1] + ws4[2] + ws4[3];
}

__global__ __launch_bounds__(256) void bscan3(int* __restrict__ bsumA) {
  int r = blockIdx.x;
  int* bsum = bsumA + r * 400;
  const int nb = (r == 1) ? 391 : 196;
  __shared__ int sh[256];
  __shared__ int runs;
  if (threadIdx.x == 0) runs = 0;
  __syncthreads();
  for (int base = 0; base < nb; base += 256) {
    int i = base + threadIdx.x;
    int v = (i < nb) ? bsum[i] : 0;
    sh[threadIdx.x] = v;
    __syncthreads();
    for (int o = 1; o < 256; o <<= 1) {
      int t = (threadIdx.x >= o) ? sh[threadIdx.x - o] : 0;
      __syncthreads();
      sh[threadIdx.x] += t;
      __syncthreads();
    }
    int incl = sh[threadIdx.x];
    int r0 = runs;
    if (i < nb) bsum[i] = r0 + incl - v;
    __syncthreads();
    if (threadIdx.x == 0) runs = r0 + sh[255];
    __syncthreads();
  }
}

__global__ __launch_bounds__(256) void rptr3(int* c0, int* c1, int* c2,
                                             const int* __restrict__ bsumA,
                                             int* r0p, int* r1p, int* r2p) {
  int b = blockIdx.x;
  int r, lb, n;
  if (b < 196)      { r = 0; lb = b;       n = NUU; }
  else if (b < 587) { r = 1; lb = b - 196; n = NTT; }
  else              { r = 2; lb = b - 587; n = NUU; }
  int* cnt = r == 0 ? c0 : r == 1 ? c1 : c2;
  int* rptr = r == 0 ? r0p : r == 1 ? r1p : r2p;
  __shared__ int sh[256];
  int i = lb * 256 + threadIdx.x;
  int v = (i < n) ? cnt[i] : 0;
  sh[threadIdx.x] = v;
  __syncthreads();
  for (int o = 1; o < 256; o <<= 1) {
    int t = (threadIdx.x >= o) ? sh[threadIdx.x - o] : 0;
    __syncthreads();
    sh[threadIdx.x] += t;
    __syncthreads();
  }
  int excl = sh[threadIdx.x] - v + bsumA[r * 400 + lb];
  if (i < n) { rptr[i] = excl; cnt[i] = excl; }
  if (i == 0) rptr[n] = EE;
}

__global__ __launch_bounds__(256) void fill3(const int* e0, const int* e1, const int* e2,
                                             int* c0, int* c1, int* c2,
                                             int* s0, int* s1, int* s2) {
  int idx = blockIdx.x * 256 + threadIdx.x;
  if (idx >= 3 * EE) return;
  int r = idx / EE, e = idx - r * EE;
  const int* ebase = (r == 0 ? e0 : r == 1 ? e1 : e2);
  int* cursor = r == 0 ? c0 : r == 1 ? c1 : c2;
  int* csrc = r == 0 ? s0 : r == 1 ? s1 : s2;
  int pos = atomicAdd(&cursor[ebase[EE + e]], 1);
  csrc[pos] = ebase[e];
}

// ---------- LDS-staged q'/V GEMM: 32 rows x 512 cols per block ----------
struct GRel3 {
  const u16* Xqb; const float* Xqf;
  const u16* Xvb; const float* Xvf;
  const u16* Wq; const u16* Wv;
  const float* bzq; const float* bzv;
  const float* cU; float* cOut;
  u16 *oq, *ov;
  int nq, nv, bq, bv, xbq, xbv;
};

__global__ __launch_bounds__(256) void gemm_rel3(GRel3 a) {
  __shared__ u16 Xs[32 * 128];
  __shared__ u16 Os[32 * 512];
  const int bx = blockIdx.x;
  int lb, n, usexb, isV;
  const u16* Xb; const float* Xf; const u16* Wsw; const float* bias; u16* Y;
  if (bx < a.bq) {
    lb = bx; n = a.nq; Xb = a.Xqb; Xf = a.Xqf; Wsw = a.Wq; bias = a.bzq; Y = a.oq;
    usexb = a.xbq; isV = 0;
  } else {
    lb = bx - a.bq; n = a.nv; Xb = a.Xvb; Xf = a.Xvf; Wsw = a.Wv; bias = a.bzv; Y = a.ov;
    usexb = a.xbv; isV = 1;
  }
  const int row0 = lb * 32;
  if (row0 >= n) return;
  const int tid = threadIdx.x;

  if (usexb) {
    #pragma unroll
    for (int q = 0; q < 2; ++q) {
      int c = tid + q * 256;
      int row = c >> 4, off = (c & 15) * 16;
      int gr = row0 + row; if (gr >= n) gr = n - 1;
      uint4 val = *(const uint4*)((const char*)Xb + (size_t)gr * 256 + off);
      *(uint4*)((char*)Xs + row * 256 + (off ^ ((row & 7) << 4))) = val;
    }
  } else {
    #pragma unroll
    for (int q = 0; q < 4; ++q) {
      int c = tid + q * 256;
      int row = c >> 5, sub = c & 31;
      int gr = row0 + row; if (gr >= n) gr = n - 1;
      float4 f = *(const float4*)(Xf + (size_t)gr * 128 + sub * 4);
      ushort4 pk;
      pk.x = f2bf(f.x); pk.y = f2bf(f.y); pk.z = f2bf(f.z); pk.w = f2bf(f.w);
      *(ushort4*)((char*)Xs + row * 256 + ((sub * 8) ^ ((row & 7) << 4))) = pk;
    }
  }
  __syncthreads();

  // ---- fused c for V blocks: 8 threads per row, vectorized b128 LDS reads ----
  if (isV && a.cOut != nullptr) {
    const int row = tid >> 3, k = tid & 7;
    const int gr = row0 + row;
    const int swz = (row & 7) << 4;
    uint4 ca = *(const uint4*)((const char*)Xs + row * 256 + ((32 * k) ^ swz));
    uint4 cb = *(const uint4*)((const char*)Xs + row * 256 + ((32 * k + 16) ^ swz));
    u32 words[8] = {ca.x, ca.y, ca.z, ca.w, cb.x, cb.y, cb.z, cb.w};
    float part[4] = {};
    #pragma unroll
    for (int wi = 0; wi < 8; ++wi) {
      int d = k * 16 + wi * 2;
      float x0 = bflo(words[wi]);
      float x1 = bfhi(words[wi]);
      #pragma unroll
      for (int h = 0; h < 4; ++h) {
        part[h] = fmaf(x0, a.cU[h * 128 + d], part[h]);
        part[h] = fmaf(x1, a.cU[h * 128 + d + 1], part[h]);
      }
    }
    #pragma unroll
    for (int h = 0; h < 4; ++h) {
      #pragma unroll
      for (int o = 1; o < 8; o <<= 1) part[h] += __shfl_xor(part[h], o);
    }
    if (k == 0 && gr < n) {
      *(float4*)(a.cOut + (size_t)gr * 4) = make_float4(part[0], part[1], part[2], part[3]);
    }
  }

  const int wid = tid >> 6, lane = tid & 63;
  const int l15 = lane & 15, l4 = lane >> 4;

  s8v afr[2][4];
  #pragma unroll
  for (int rt = 0; rt < 2; ++rt) {
    int row = rt * 16 + l15;
    #pragma unroll
    for (int kk = 0; kk < 4; ++kk)
      afr[rt][kk] = *(const s8v*)((const char*)Xs + row * 256 + ((kk * 64 + l4 * 16) ^ ((row & 7) << 4)));
  }

  const u16* wbase = Wsw + ((size_t)wid * 16384) + (size_t)lane * 8;
  s8v w0[4], w1[4];
  #pragma unroll
  for (int kk = 0; kk < 4; ++kk) w0[kk] = *(const s8v*)(wbase + kk * 512);

  #pragma unroll
  for (int ctl = 0; ctl < 8; ++ctl) {
    const s8v* cw = (ctl & 1) ? w1 : w0;
    s8v* nw = (ctl & 1) ? w0 : w1;
    if (ctl + 1 < 8) {
      #pragma unroll
      for (int kk = 0; kk < 4; ++kk)
        nw[kk] = *(const s8v*)(wbase + (ctl + 1) * 2048 + kk * 512);
    }
    f4v acc0 = {}, acc1 = {};
    #pragma unroll
    for (int kk = 0; kk < 4; ++kk) {
      acc0 = __builtin_amdgcn_mfma_f32_16x16x32_bf16(cw[kk], afr[0][kk], acc0, 0, 0, 0);
      acc1 = __builtin_amdgcn_mfma_f32_16x16x32_bf16(cw[kk], afr[1][kk], acc1, 0, 0, 0);
    }
    const int colb = wid * 128 + ctl * 16 + l4 * 4;
    const float4 bb = *(const float4*)(bias + colb);
    {
      int row = l15;
      ushort4 pk;
      pk.x = f2bf(acc0[0] + bb.x); pk.y = f2bf(acc0[1] + bb.y);
      pk.z = f2bf(acc0[2] + bb.z); pk.w = f2bf(acc0[3] + bb.w);
      *(ushort4*)((char*)Os + row * 1024 + ((colb * 2) ^ ((row & 7) << 4))) = pk;
    }
    {
      int row = 16 + l15;
      ushort4 pk;
      pk.x = f2bf(acc1[0] + bb.x); pk.y = f2bf(acc1[1] + bb.y);
      pk.z = f2bf(acc1[2] + bb.z); pk.w = f2bf(acc1[3] + bb.w);
      *(ushort4*)((char*)Os + row * 1024 + ((colb * 2) ^ ((row & 7) << 4))) = pk;
    }
  }
  __syncthreads();

  #pragma unroll
  for (int r = 0; r < 8; ++r) {
    int row = wid * 8 + r;
    int gr = row0 + row;
    if (gr < n) {
      uint4 val = *(const uint4*)((const char*)Os + row * 1024 + ((lane * 16) ^ ((row & 7) << 4)));
      *(uint4*)(Y + (size_t)gr * 512 + lane * 8) = val;
    }
  }
}

// ---------- skip GEMM (flat grid, STORE) ----------
__global__ __launch_bounds__(256) void gemm_skip3(const u16* xbu, const u16* xbt,
                                                  const float* xfu, const float* xft,
                                                  const u16* Wu, const u16* Wtw,
                                                  const float* bu, const float* btw,
                                                  float* aggu, float* aggt,
                                                  int fu, int ft) {
  const int bx = blockIdx.x;
  int job, lb;
  if (bx < BU) { job = 0; lb = bx; } else { job = 1; lb = bx - BU; }
  const int n = job ? NTT : NUU;
  const int bm = lb * 128;
  const u16* XB = job ? xbt : xbu;
  const float* XF = job ? xft : xfu;
  const u16* Wt = job ? Wtw : Wu;
  const float* bias = job ? btw : bu;
  float* out = job ? aggt : aggu;
  const int usexb = job ? ft : fu;

  const int wid = threadIdx.x >> 6, lane = threadIdx.x & 63;
  const int l15 = lane & 15, l4 = lane >> 4;
  const int rbase = bm + wid * 32;
  int r0 = rbase + l15;      if (r0 >= n) r0 = n - 1;
  int r1 = rbase + 16 + l15; if (r1 >= n) r1 = n - 1;
  s8v a0[4], a1[4];
  if (usexb) {
    const u16* xb0 = XB + (size_t)r0 * DD + l4 * 8;
    const u16* xb1 = XB + (size_t)r1 * DD + l4 * 8;
    #pragma unroll
    for (int kk = 0; kk < 4; ++kk) {
      a0[kk] = *(const s8v*)(xb0 + kk * 32);
      a1[kk] = *(const s8v*)(xb1 + kk * 32);
    }
  } else {
    const float* xp0 = XF + (size_t)r0 * DD + l4 * 8;
    const float* xp1 = XF + (size_t)r1 * DD + l4 * 8;
    #pragma unroll
    for (int kk = 0; kk < 4; ++kk) {
      a0[kk] = cvt_row8(xp0 + kk * 32);
      a1[kk] = cvt_row8(xp1 + kk * 32);
    }
  }

  const u16* wp = Wt + (size_t)l15 * DD + l4 * 8;
  const bool ok0 = (rbase + l15 < n), ok1 = (rbase + 16 + l15 < n);
  float* yp0 = out + (size_t)(rbase + l15) * DD + l4 * 8;
  float* yp1 = out + (size_t)(rbase + 16 + l15) * DD + l4 * 8;

  s8v w0[8], w1[8];
  #pragma unroll
  for (int kk = 0; kk < 4; ++kk) {
    w0[kk]     = *(const s8v*)(wp + kk * 32);
    w0[4 + kk] = *(const s8v*)(wp + 16 * DD + kk * 32);
  }
  #pragma unroll
  for (int p = 0; p < 4; ++p) {
    const s8v* cw = (p & 1) ? w1 : w0;
    s8v* nw = (p & 1) ? w0 : w1;
    if (p + 1 < 4) {
      const u16* wq = wp + (size_t)(2 * (p + 1)) * 16 * DD;
      #pragma unroll
      for (int kk = 0; kk < 4; ++kk) {
        nw[kk]     = *(const s8v*)(wq + kk * 32);
        nw[4 + kk] = *(const s8v*)(wq + 16 * DD + kk * 32);
      }
    }
    f4v aE0 = {}, aE1 = {}, aO0 = {}, aO1 = {};
    #pragma unroll
    for (int kk = 0; kk < 4; ++kk) {
      aE0 = __builtin_amdgcn_mfma_f32_16x16x32_bf16(cw[kk], a0[kk], aE0, 0, 0, 0);
      aE1 = __builtin_amdgcn_mfma_f32_16x16x32_bf16(cw[kk], a1[kk], aE1, 0, 0, 0);
      aO0 = __builtin_amdgcn_mfma_f32_16x16x32_bf16(cw[4 + kk], a0[kk], aO0, 0, 0, 0);
      aO1 = __builtin_amdgcn_mfma_f32_16x16x32_bf16(cw[4 + kk], a1[kk], aO1, 0, 0, 0);
    }
    const float4 bbE = *(const float4*)(bias + p * 32 + l4 * 8);
    const float4 bbO = *(const float4*)(bias + p * 32 + l4 * 8 + 4);
    if (ok0) {
      *(float4*)(yp0 + p * 32) = make_float4(aE0[0] + bbE.x, aE0[1] + bbE.y, aE0[2] + bbE.z, aE0[3] + bbE.w);
      *(float4*)(yp0 + p * 32 + 4) = make_float4(aO0[0] + bbO.x, aO0[1] + bbO.y, aO0[2] + bbO.z, aO0[3] + bbO.w);
    }
    if (ok1) {
      *(float4*)(yp1 + p * 32) = make_float4(aE1[0] + bbE.x, aE1[1] + bbE.y, aE1[2] + bbE.z, aE1[3] + bbE.w);
      *(float4*)(yp1 + p * 32 + 4) = make_float4(aO1[0] + bbO.x, aO1[1] + bbO.y, aO1[2] + bbO.z, aO1[3] + bbO.w);
    }
  }
}

// ---------- edge kernel: logits via q'.x_s + c(s); V gather; deg-1 fast path ----------
template<int XF>
__global__ __launch_bounds__(256) void edge_fused2(const u16* __restrict__ qp,
                                                   const u16* __restrict__ v,
                                                   const u16* __restrict__ xsb,
                                                   const float* __restrict__ xsf,
                                                   const float* __restrict__ cbuf,
                                                   const int* __restrict__ rptr,
                                                   const int* __restrict__ csrc,
                                                   float* __restrict__ agg,
                                                   int nd, int qs32) {
  int node = (int)(((size_t)blockIdx.x * 256 + threadIdx.x) >> 6);
  int lane = threadIdx.x & 63;
  if (node >= nd) return;
  int e0 = rptr[node], e1 = rptr[node + 1];
  if (e0 == e1) return;
  const int g = lane >> 4, i = lane & 15;
  float acc[8];

  if (e1 - e0 == 1) {
    int s = csrc[e0];
    const u32* vp = (const u32*)v + (size_t)s * 256 + lane * 4;
    #pragma unroll
    for (int j = 0; j < 4; ++j) { u32 u = vp[j]; acc[2 * j] = bflo(u); acc[2 * j + 1] = bfhi(u); }
  } else {
    u32 qv[4];
    {
      const u32* qq = (const u32*)qp + (size_t)node * qs32 + g * 64 + i * 4;
      #pragma unroll
      for (int j = 0; j < 4; ++j) qv[j] = qq[j];
    }
    float m = -1e30f, z = 0.f;
    #pragma unroll
    for (int j = 0; j < 8; ++j) acc[j] = 0.f;

    int s_cur = csrc[e0];
    u32 xc[4]; float xf[8];
    if (XF) {
      const u32* xp = (const u32*)xsb + (size_t)s_cur * 64 + i * 4;
      #pragma unroll
      for (int j = 0; j < 4; ++j) xc[j] = xp[j];
    } else {
      const float* xp = xsf + (size_t)s_cur * 128 + i * 8;
      #pragma unroll
      for (int j = 0; j < 8; ++j) xf[j] = xp[j];
    }

    for (int e = e0; e < e1; ++e) {
      u32 vcur[4];
      {
        const u32* vp = (const u32*)v + (size_t)s_cur * 256 + lane * 4;
        #pragma unroll
        for (int j = 0; j < 4; ++j) vcur[j] = vp[j];
      }
      float cs = cbuf[(size_t)s_cur * 4 + g];
      const bool has = (e + 1 < e1);
      int s_nxt = csrc[has ? e + 1 : e0];
      u32 xn[4]; float xnf[8];
      if (XF) {
        const u32* xp = (const u32*)xsb + (size_t)s_nxt * 64 + i * 4;
        #pragma unroll
        for (int j = 0; j < 4; ++j) xn[j] = xp[j];
      } else {
        const float* xp = xsf + (size_t)s_nxt * 128 + i * 8;
        #pragma unroll
        for (int j = 0; j < 8; ++j) xnf[j] = xp[j];
      }

      float dot = 0.f;
      if (XF) {
        #pragma unroll
        for (int j = 0; j < 4; ++j)
          dot += bflo(qv[j]) * bflo(xc[j]) + bfhi(qv[j]) * bfhi(xc[j]);
      } else {
        #pragma unroll
        for (int j = 0; j < 4; ++j)
          dot += bflo(qv[j]) * xf[2 * j] + bfhi(qv[j]) * xf[2 * j + 1];
      }
      dot += __shfl_xor(dot, 1);
      dot += __shfl_xor(dot, 2);
      dot += __shfl_xor(dot, 4);
      dot += __shfl_xor(dot, 8);
      float lg = dot * 0.08838834764831845f + cs;
      float w;
      if (lg > m) {
        float sc = __expf(m - lg);
        z *= sc;
        #pragma unroll
        for (int j = 0; j < 8; ++j) acc[j] *= sc;
        m = lg; w = 1.f;
      } else {
        w = __expf(lg - m);
      }
      z += w;
      #pragma unroll
      for (int j = 0; j < 4; ++j) {
        acc[2 * j]     += w * bflo(vcur[j]);
        acc[2 * j + 1] += w * bfhi(vcur[j]);
      }
      if (has) {
        s_cur = s_nxt;
        if (XF) {
          #pragma unroll
          for (int j = 0; j < 4; ++j) xc[j] = xn[j];
        } else {
          #pragma unroll
          for (int j = 0; j < 8; ++j) xf[j] = xnf[j];
        }
      }
    }
    float iz = 1.f / z;
    #pragma unroll
    for (int j = 0; j < 8; ++j) acc[j] *= iz;
  }

  #pragma unroll
  for (int j = 0; j < 8; ++j) acc[j] *= 0.25f;
  #pragma unroll
  for (int o = 16; o < 64; o <<= 1) {
    #pragma unroll
    for (int j = 0; j < 8; ++j) acc[j] += __shfl_xor(acc[j], o);
  }
  if (lane < 16) {
    float* op = agg + (size_t)node * DD + lane * 8;
    #pragma unroll
    for (int j = 0; j < 8; ++j) op[j] += acc[j];
  }
}

// ---------- l0-tu shortcut: uniform softmax over broadcast K/V ----------
__global__ __launch_bounds__(256) void add_bcast4(const u16* __restrict__ v,
                                                  const int* __restrict__ rptr,
                                                  float* __restrict__ agg, int nd) {
  int node = (int)(((size_t)blockIdx.x * 256 + threadIdx.x) >> 6);
  int lane = threadIdx.x & 63;
  if (node >= nd) return;
  if (rptr[node + 1] <= rptr[node]) return;
  const u32* vp = (const u32*)v;   // row 0
  float a0 = 0.f, a1 = 0.f;
  #pragma unroll
  for (int h = 0; h < 4; ++h) {
    u32 u = vp[h * 64 + lane];
    a0 += bflo(u); a1 += bfhi(u);
  }
  float* op = agg + (size_t)node * DD + 2 * lane;
  op[0] += 0.25f * a0;
  op[1] += 0.25f * a1;
}

// ---------- LayerNorm + residual (explicit residual src, bf16 mirror writes) ----------
// residual for node row r: ru[r*DD + col] (users), rt[r*rts + col] (tweets; rts=0 => broadcast)
__global__ __launch_bounds__(256) void ln2(const float* __restrict__ aggu,
                                           const float* __restrict__ aggt,
                                           const float* __restrict__ g2,
                                           const float* __restrict__ b2,
                                           const float* __restrict__ ru,
                                           const float* __restrict__ rt,
                                           int rts,
                                           float* __restrict__ xu,
                                           float* __restrict__ xt,
                                           u16* __restrict__ xbu,
                                           u16* __restrict__ xbt,
                                           int wbu, int wbt) {
  int wid = (int)(((size_t)blockIdx.x * 256 + threadIdx.x) >> 6);
  int lane = threadIdx.x & 63;
  if (wid >= NUU + NTT) return;
  const float* ap; float* xp; const float* g; const float* b; u16* xbp; int wb;
  const float* rp;
  if (wid < NUU) {
    ap = aggu + (size_t)wid * DD; xp = xu + (size_t)wid * DD;
    rp = ru + (size_t)wid * DD;
    xbp = xbu ? xbu + (size_t)wid * DD : nullptr; g = g2; b = b2; wb = wbu;
  } else {
    int t = wid - NUU;
    ap = aggt + (size_t)t * DD; xp = xt + (size_t)t * DD;
    rp = rt + (size_t)t * rts;
    xbp = xbt ? xbt + (size_t)t * DD : nullptr; g = g2 + DD; b = b2 + DD; wb = wbt;
  }
  float2 va = *(const float2*)(ap + 2 * lane);
  float v0 = va.x, v1 = va.y;
  float s = v0 + v1;
  #pragma unroll
  for (int o = 1; o < 64; o <<= 1) s += __shfl_xor(s, o);
  float mean = s * (1.0f / DD);
  float d0 = v0 - mean, d1 = v1 - mean;
  float sq = d0 * d0 + d1 * d1;
  #pragma unroll
  for (int o = 1; o < 64; o <<= 1) sq += __shfl_xor(sq, o);
  float rstd = rsqrtf(sq * (1.0f / DD) + 1e-5f);
  float2 xv = *(const float2*)(rp + 2 * lane);
  float2 gv = *(const float2*)(g + 2 * lane);
  float2 bv = *(const float2*)(b + 2 * lane);
  float n0 = gv.x * d0 * rstd + bv.x + xv.x;
  float n1 = gv.y * d1 * rstd + bv.y + xv.y;
  *(float2*)(xp + 2 * lane) = make_float2(n0, n1);
  if (wb) {
    *(u32*)(xbp + 2 * lane) = (u32)f2bf(n0) | ((u32)f2bf(n1) << 16);
  }
}

extern "C" void kernel_launch(void* const* d_in, const int* in_sizes, int n_in,
                              void* d_out, int out_size, void* d_ws, size_t ws_size,
                              hipStream_t stream) {
  const float* emb_user = (const float*)d_in[0];
  const float* tv_tweet = (const float*)d_in[1];
  const float* W_qkv  = (const float*)d_in[2];
  const float* b_qkv  = (const float*)d_in[3];
  const float* W_skip = (const float*)d_in[4];
  const float* b_skip = (const float*)d_in[5];
  const float* ln_g   = (const float*)d_in[6];
  const float* ln_b   = (const float*)d_in[7];
  const int* edges[3] = { (const int*)d_in[8], (const int*)d_in[9], (const int*)d_in[10] };

  float* x_user  = (float*)d_out;
  float* x_tweet = x_user + (size_t)NUU * DD;

  // ---- workspace layout (identical to R12/R14/R15) ----
  const size_t fixed = 786432 + 131072 + 2048 + 786432 + 12288 + 2048 + 1600000
                     + 76800000 + (size_t)3 * 400032 + (size_t)3 * 400000 + 4800
                     + 153600000 + 4096;
  int XBU = 0, XBT = 0;
  if      (ws_size >= fixed + 38400000) { XBU = 1; XBT = 1; }
  else if (ws_size >= fixed + 25600000) { XBT = 1; }

  char* w = (char*)d_ws;
  u16* Wtv = (u16*)w;        w += 786432;
  u16* WtsC = (u16*)w;       w += 131072;
  float* bskC = (float*)w;   w += 2048;
  u16* Mwt = (u16*)w;        w += 786432;
  float* Uw = (float*)w;     w += 12288;
  float* zeros = (float*)w;  w += 2048;
  float* cbuf = (float*)w;   w += 1600000;
  float* agg_u = (float*)w;  w += (size_t)NUU * DD * 4;
  float* agg_t = (float*)w;  w += (size_t)NTT * DD * 4;
  int* rptrA[3]; int* csrcA[3];
  for (int r = 0; r < 3; ++r) { rptrA[r] = (int*)w; w += 400032; }
  for (int r = 0; r < 3; ++r) { csrcA[r] = (int*)w; w += 400000; }
  int* bsumA = (int*)w;      w += 4800;
  u16* xb_user = nullptr; u16* xb_tweet = nullptr;
  if (XBT) { xb_tweet = (u16*)w; w += (size_t)NTT * DD * 2; }
  if (XBU) { xb_user = (u16*)w;  w += (size_t)NUU * DD * 2; }
  u16* arena = (u16*)w;
  int* cntA[3];
  cntA[0] = (int*)arena; cntA[1] = cntA[0] + 100000; cntA[2] = cntA[0] + 200000;

  init_x2<<<(19500000 + 255) / 256, 256, 0, stream>>>(emb_user, tv_tweet, x_user, x_tweet,
                                                      cntA[0], xb_user, xb_tweet, XBU, XBT);
  conv_w<<<(6 * 65536 + 255) / 256, 256, 0, stream>>>(W_qkv, W_skip, b_skip,
                                                      Wtv, WtsC, bskC, zeros);
  mk_m2<<<dim3(24, 8), 256, 0, stream>>>(W_qkv, b_qkv, Mwt, Uw);

  hist3<<<(3 * EE + 255) / 256, 256, 0, stream>>>(edges[0], edges[1], edges[2],
                                                  cntA[0], cntA[1], cntA[2]);
  bsum3<<<783, 256, 0, stream>>>(cntA[0], cntA[1], cntA[2], bsumA);
  bscan3<<<3, 256, 0, stream>>>(bsumA);
  rptr3<<<783, 256, 0, stream>>>(cntA[0], cntA[1], cntA[2], bsumA, rptrA[0], rptrA[1], rptrA[2]);
  fill3<<<(3 * EE + 255) / 256, 256, 0, stream>>>(edges[0], edges[1], edges[2],
                                                  cntA[0], cntA[1], cntA[2],
                                                  csrcA[0], csrcA[1], csrcA[2]);

  const int stt[3] = {0, 0, 1}, dtt[3] = {0, 1, 0};
  const int cnt2[2] = {NUU, NTT};
  float* xs[2]   = {x_user, x_tweet};
  u16* xbs[2]    = {xb_user, xb_tweet};
  const int xbf[2] = {XBU, XBT};
  float* aggs[2] = {agg_u, agg_t};

  for (int l = 0; l < 2; ++l) {
    gemm_skip3<<<BU + BT, 256, 0, stream>>>(
        xb_user, xb_tweet, x_user, x_tweet,
        WtsC + (size_t)(2 * l) * 128 * 128, WtsC + (size_t)(2 * l + 1) * 128 * 128,
        bskC + (size_t)(2 * l) * 128, bskC + (size_t)(2 * l + 1) * 128,
        agg_u, agg_t, XBU, XBT);

    for (int r = 0; r < 3; ++r) {
      const int st = stt[r], dt = dtt[r];
      const int ns = cnt2[st], nd = cnt2[dt];
      const int rel = l * 3 + r;
      const bool qDeg = (l == 0 && dt == 1);   // ut-l0: broadcast dst
      const bool uniSM = (l == 0 && st == 1);  // tu-l0: broadcast src -> uniform softmax

      const int nq_eff = uniSM ? 0 : (qDeg ? 1 : nd);
      const int nv_eff = uniSM ? 1 : ns;
      u16* qb_r = arena;
      u16* vb_r = arena + (size_t)nq_eff * HCC;

      GRel3 ga;
      ga.Xqb = xbs[dt]; ga.Xqf = xs[dt]; ga.xbq = xbf[dt];
      ga.Xvb = xbs[st]; ga.Xvf = xs[st]; ga.xbv = xbf[st];
      ga.Wq = Mwt + (size_t)rel * 65536;
      ga.Wv = Wtv + (size_t)rel * 65536;
      ga.bzq = zeros;
      ga.bzv = b_qkv + (size_t)(rel * 3 + 2) * HCC;
      ga.cU = Uw + (size_t)rel * 512;
      ga.cOut = uniSM ? nullptr : cbuf;
      ga.oq = qb_r; ga.ov = vb_r;
      ga.nq = nq_eff; ga.nv = nv_eff;
      ga.bq = (nq_eff + 31) / 32; ga.bv = (nv_eff + 31) / 32;
      gemm_rel3<<<ga.bq + ga.bv, 256, 0, stream>>>(ga);

      const int eblk = (nd + 3) / 4;
      if (uniSM) {
        add_bcast4<<<eblk, 256, 0, stream>>>(vb_r, rptrA[r], aggs[dt], nd);
      } else {
        const int qs32 = qDeg ? 0 : 256;
        if (xbf[st])
          edge_fused2<1><<<eblk, 256, 0, stream>>>(qb_r, vb_r, xbs[st], xs[st], cbuf,
                                                   rptrA[r], csrcA[r], aggs[dt], nd, qs32);
        else
          edge_fused2<0><<<eblk, 256, 0, stream>>>(qb_r, vb_r, xbs[st], xs[st], cbuf,
                                                   rptrA[r], csrcA[r], aggs[dt], nd, qs32);
      }
    }
    // residual source: layer 0 reads the immutable inputs (emb / broadcast tv);
    // layer 1 reads the layer-0 outputs in x. (f32 x is first written by ln2-l0
    // when mirrors are active.)
    const float* ru = (l == 0 && XBU) ? emb_user : x_user;
    const float* rt = (l == 0 && XBT) ? tv_tweet : x_tweet;
    const int rts = (l == 0 && XBT) ? 0 : DD;
    ln2<<<(NUU + NTT + 3) / 4, 256, 0, stream>>>(agg_u, agg_t,
                                                 ln_g + (size_t)l * 2 * DD,
                                                 ln_b + (size_t)l * 2 * DD,
                                                 ru, rt, rts,
                                                 x_user, x_tweet,
                                                 xb_user, xb_tweet,
                                                 XBU && l == 0, XBT && l == 0);
  }
}

// Round 17
// 648.093 us; speedup vs baseline: 1.0248x; 1.0221x over previous
//
#include <hip/hip_runtime.h>
#include <hip/hip_bf16.h>
#include <math.h>

typedef unsigned short u16;
typedef unsigned int   u32;
typedef __attribute__((ext_vector_type(8))) short s8v;    // 8 x bf16
typedef __attribute__((ext_vector_type(8))) unsigned short u16x8;
typedef __attribute__((ext_vector_type(4))) float f4v;    // MFMA accumulator

#define NUU 50000
#define NTT 100000
#define EE  100000
#define DD  128
#define HH  4
#define HCC 512
#define BU  391
#define BT  782

// ---------- helpers ----------
__device__ __forceinline__ float bflo(u32 u) { return __uint_as_float(u << 16); }
__device__ __forceinline__ float bfhi(u32 u) { return __uint_as_float(u & 0xFFFF0000u); }
__device__ __forceinline__ u16 f2bf(float f) {
  u32 u = __float_as_uint(f);
  u32 r = (u + 0x7FFFu + ((u >> 16) & 1u)) >> 16;
  return (u16)r;
}
__device__ __forceinline__ s8v cvt_row8(const float* __restrict__ p) {
  float4 u = *(const float4*)p;
  float4 v = *(const float4*)(p + 4);
  s8v r;
  r[0] = (short)f2bf(u.x); r[1] = (short)f2bf(u.y);
  r[2] = (short)f2bf(u.z); r[3] = (short)f2bf(u.w);
  r[4] = (short)f2bf(v.x); r[5] = (short)f2bf(v.y);
  r[6] = (short)f2bf(v.z); r[7] = (short)f2bf(v.w);
  return r;
}
__device__ __forceinline__ int colperm(int c) {   // used by skip GEMM
  return (c & ~31) | (((c >> 2) & 3) << 3) | (((c >> 4) & 1) << 2) | (c & 3);
}

// ---------- init: mirrors (or f32 x in fallback) + zero cnt ----------
__global__ __launch_bounds__(256) void init_x2(const float* __restrict__ emb,
                                               const float* __restrict__ tv,
                                               float* __restrict__ xu,
                                               float* __restrict__ xt,
                                               int* __restrict__ cz,
                                               u16* __restrict__ xbu,
                                               u16* __restrict__ xbt,
                                               int fu, int ft) {
  size_t idx = (size_t)blockIdx.x * 256 + threadIdx.x;
  const size_t nu = (size_t)NUU * DD;
  const size_t nt = (size_t)NTT * DD;
  if (idx < nu) {
    float v = emb[idx];
    if (fu) xbu[idx] = f2bf(v);   // mirror path: f32 x first written by ln2-l0
    else    xu[idx] = v;
  } else if (idx < nu + nt) {
    size_t j = idx - nu;
    float v = tv[j & (DD - 1)];
    if (ft) xbt[j] = f2bf(v);
    else    xt[j] = v;
  } else {
    size_t j = idx - (nu + nt);
    if (j < 300000) cz[j] = 0;
  }
}

// ---------- weights: Wtv fragment-swizzled; combined skip W; zeros ----------
__global__ __launch_bounds__(256) void conv_w(const float* __restrict__ Wq,
                                              const float* __restrict__ Wsk,
                                              const float* __restrict__ bsk,
                                              u16* __restrict__ Wtv,
                                              u16* __restrict__ WtsC,
                                              float* __restrict__ bskC,
                                              float* __restrict__ zeros) {
  int idx = blockIdx.x * 256 + threadIdx.x;
  if (idx < 6 * 65536) {
    int mat = idx >> 16, pos = idx & 65535;
    int e = pos & 7, lane = (pos >> 3) & 63, kk = (pos >> 9) & 3, ct = pos >> 11;
    int col = ct * 16 + (lane & 15);
    int k = kk * 32 + (lane >> 4) * 8 + e;
    Wtv[idx] = f2bf(Wq[((size_t)(mat * 3 + 2) * 128 + k) * 512 + col]);
  }
  if (idx < 4 * 128 * 128) {
    int k = idx & 127, cp = (idx >> 7) & 127, m = idx >> 14;
    int l = m >> 1, isT = m & 1, col = colperm(cp);
    float v;
    if (isT) v = Wsk[((size_t)(l * 3 + 1) * 128 + k) * 128 + col];
    else     v = Wsk[((size_t)(l * 3 + 0) * 128 + k) * 128 + col]
               + Wsk[((size_t)(l * 3 + 2) * 128 + k) * 128 + col];
    WtsC[idx] = f2bf(v);
  }
  if (idx < 4 * 128) {
    int m = idx >> 7, c = idx & 127;
    int l = m >> 1, isT = m & 1;
    bskC[idx] = isT ? bsk[(size_t)(l * 3 + 1) * 128 + c]
                    : bsk[(size_t)(l * 3 + 0) * 128 + c] + bsk[(size_t)(l * 3 + 2) * 128 + c];
  }
  if (idx < 512) zeros[idx] = 0.f;
}

// ---------- M = Wq_h @ Wk_h^T (swizzled output) + U = Wk_h @ bq_h ----------
__global__ __launch_bounds__(256) void mk_m2(const float* __restrict__ Wq_all,
                                             const float* __restrict__ bq_all,
                                             u16* __restrict__ Mwt,
                                             float* __restrict__ Uw) {
  const int rel = blockIdx.x >> 2, h = blockIdx.x & 3;
  const int cpB = blockIdx.y;
  const float* Wq = Wq_all + (size_t)(rel * 3 + 0) * 128 * 512 + h * 128;
  const float* Wk = Wq_all + (size_t)(rel * 3 + 1) * 128 * 512 + h * 128;
  const float* bq = bq_all + (size_t)(rel * 3 + 0) * 512 + h * 128;

  __shared__ float Qs[128][129];
  __shared__ float Ks[16][129];
  for (int idx = threadIdx.x; idx < 16384; idx += 256) {
    int a = idx >> 7, c = idx & 127;
    Qs[a][c] = Wq[(size_t)a * 512 + c];
  }
  for (int idx = threadIdx.x; idx < 2048; idx += 256) {
    int row = idx >> 7, c = idx & 127;
    int d = cpB * 16 + row;
    Ks[row][c] = Wk[(size_t)d * 512 + c];
  }
  __syncthreads();

  const int a = threadIdx.x & 127;
  const int rsel = threadIdx.x >> 7;
  float acc[8] = {};
  for (int c = 0; c < 128; ++c) {
    float qa = Qs[a][c];
    #pragma unroll
    for (int j = 0; j < 8; ++j) acc[j] = fmaf(qa, Ks[rsel * 8 + j][c], acc[j]);
  }
  const int kk = a >> 5, l4a = (a >> 3) & 3, e = a & 7;
  #pragma unroll
  for (int j = 0; j < 8; ++j) {
    int d = cpB * 16 + rsel * 8 + j;
    int col = h * 128 + d;
    int ct = col >> 4, l15c = col & 15;
    int lane = l4a * 16 + l15c;
    Mwt[(size_t)rel * 65536 + ((size_t)(ct * 4 + kk) * 64 + lane) * 8 + e] = f2bf(acc[j]);
  }

  if (cpB == 0 && threadIdx.x < 128) {
    int d = threadIdx.x;
    float s = 0.f;
    for (int c = 0; c < 128; ++c) s = fmaf(Wk[(size_t)d * 512 + c], bq[c], s);
    Uw[((size_t)rel * 4 + h) * 128 + d] = s * 0.08838834764831845f;
  }
}

// ---------- CSR build ----------
__global__ __launch_bounds__(256) void hist3(const int* e0, const int* e1, const int* e2,
                                             int* c0, int* c1, int* c2) {
  int idx = blockIdx.x * 256 + threadIdx.x;
  if (idx >= 3 * EE) return;
  int r = idx / EE, e = idx - r * EE;
  const int* edst = (r == 0 ? e0 : r == 1 ? e1 : e2) + EE;
  int* cnt = r == 0 ? c0 : r == 1 ? c1 : c2;
  atomicAdd(&cnt[edst[e]], 1);
}

__global__ __launch_bounds__(256) void bsum3(const int* c0, const int* c1, const int* c2,
                                             int* __restrict__ bsumA) {
  int b = blockIdx.x;
  int r, lb, n;
  if (b < 196)      { r = 0; lb = b;       n = NUU; }
  else if (b < 587) { r = 1; lb = b - 196; n = NTT; }
  else              { r = 2; lb = b - 587; n = NUU; }
  const int* cnt = r == 0 ? c0 : r == 1 ? c1 : c2;
  int i = lb * 256 + threadIdx.x;
  int v = (i < n) ? cnt[i] : 0;
  #pragma unroll
  for (int o = 1; o < 64; o <<= 1) v += __shfl_xor(v, o);
  __shared__ int ws4[4];
  if ((threadIdx.x & 63) == 0) ws4[threadIdx.x >> 6] = v;
  __syncthreads();
  if (threadIdx.x == 0) bsumA[r * 400 + lb] = ws4[0] + ws4[1] + ws4[2] + ws4[3];
}

__global__ __launch_bounds__(256) void bscan3(int* __restrict__ bsumA) {
  int r = blockIdx.x;
  int* bsum = bsumA + r * 400;
  const int nb = (r == 1) ? 391 : 196;
  __shared__ int sh[256];
  __shared__ int runs;
  if (threadIdx.x == 0) runs = 0;
  __syncthreads();
  for (int base = 0; base < nb; base += 256) {
    int i = base + threadIdx.x;
    int v = (i < nb) ? bsum[i] : 0;
    sh[threadIdx.x] = v;
    __syncthreads();
    for (int o = 1; o < 256; o <<= 1) {
      int t = (threadIdx.x >= o) ? sh[threadIdx.x - o] : 0;
      __syncthreads();
      sh[threadIdx.x] += t;
      __syncthreads();
    }
    int incl = sh[threadIdx.x];
    int r0 = runs;
    if (i < nb) bsum[i] = r0 + incl - v;
    __syncthreads();
    if (threadIdx.x == 0) runs = r0 + sh[255];
    __syncthreads();
  }
}

__global__ __launch_bounds__(256) void rptr3(int* c0, int* c1, int* c2,
                                             const int* __restrict__ bsumA,
                                             int* r0p, int* r1p, int* r2p) {
  int b = blockIdx.x;
  int r, lb, n;
  if (b < 196)      { r = 0; lb = b;       n = NUU; }
  else if (b < 587) { r = 1; lb = b - 196; n = NTT; }
  else              { r = 2; lb = b - 587; n = NUU; }
  int* cnt = r == 0 ? c0 : r == 1 ? c1 : c2;
  int* rptr = r == 0 ? r0p : r == 1 ? r1p : r2p;
  __shared__ int sh[256];
  int i = lb * 256 + threadIdx.x;
  int v = (i < n) ? cnt[i] : 0;
  sh[threadIdx.x] = v;
  __syncthreads();
  for (int o = 1; o < 256; o <<= 1) {
    int t = (threadIdx.x >= o) ? sh[threadIdx.x - o] : 0;
    __syncthreads();
    sh[threadIdx.x] += t;
    __syncthreads();
  }
  int excl = sh[threadIdx.x] - v + bsumA[r * 400 + lb];
  if (i < n) { rptr[i] = excl; cnt[i] = excl; }
  if (i == 0) rptr[n] = EE;
}

__global__ __launch_bounds__(256) void fill3(const int* e0, const int* e1, const int* e2,
                                             int* c0, int* c1, int* c2,
                                             int* s0, int* s1, int* s2) {
  int idx = blockIdx.x * 256 + threadIdx.x;
  if (idx >= 3 * EE) return;
  int r = idx / EE, e = idx - r * EE;
  const int* ebase = (r == 0 ? e0 : r == 1 ? e1 : e2);
  int* cursor = r == 0 ? c0 : r == 1 ? c1 : c2;
  int* csrc = r == 0 ? s0 : r == 1 ? s1 : s2;
  int pos = atomicAdd(&cursor[ebase[EE + e]], 1);
  csrc[pos] = ebase[e];
}

// ---------- LDS-staged q'/V GEMM: 32 rows x 512 cols per block ----------
// V branch fuses c; Q branch optionally skips stores for deg<2 rows (qrptr).
struct GRel3 {
  const u16* Xqb; const float* Xqf;
  const u16* Xvb; const float* Xvf;
  const u16* Wq; const u16* Wv;
  const float* bzq; const float* bzv;
  const float* cU; float* cOut;
  const int* qrptr;                 // null => always store q' rows
  u16 *oq, *ov;
  int nq, nv, bq, bv, xbq, xbv;
};

__global__ __launch_bounds__(256) void gemm_rel3(GRel3 a) {
  __shared__ u16 Xs[32 * 128];
  __shared__ u16 Os[32 * 512];
  const int bx = blockIdx.x;
  int lb, n, usexb, isV;
  const u16* Xb; const float* Xf; const u16* Wsw; const float* bias; u16* Y;
  if (bx < a.bq) {
    lb = bx; n = a.nq; Xb = a.Xqb; Xf = a.Xqf; Wsw = a.Wq; bias = a.bzq; Y = a.oq;
    usexb = a.xbq; isV = 0;
  } else {
    lb = bx - a.bq; n = a.nv; Xb = a.Xvb; Xf = a.Xvf; Wsw = a.Wv; bias = a.bzv; Y = a.ov;
    usexb = a.xbv; isV = 1;
  }
  const int row0 = lb * 32;
  if (row0 >= n) return;
  const int tid = threadIdx.x;

  if (usexb) {
    #pragma unroll
    for (int q = 0; q < 2; ++q) {
      int c = tid + q * 256;
      int row = c >> 4, off = (c & 15) * 16;
      int gr = row0 + row; if (gr >= n) gr = n - 1;
      uint4 val = *(const uint4*)((const char*)Xb + (size_t)gr * 256 + off);
      *(uint4*)((char*)Xs + row * 256 + (off ^ ((row & 7) << 4))) = val;
    }
  } else {
    #pragma unroll
    for (int q = 0; q < 4; ++q) {
      int c = tid + q * 256;
      int row = c >> 5, sub = c & 31;
      int gr = row0 + row; if (gr >= n) gr = n - 1;
      float4 f = *(const float4*)(Xf + (size_t)gr * 128 + sub * 4);
      ushort4 pk;
      pk.x = f2bf(f.x); pk.y = f2bf(f.y); pk.z = f2bf(f.z); pk.w = f2bf(f.w);
      *(ushort4*)((char*)Xs + row * 256 + ((sub * 8) ^ ((row & 7) << 4))) = pk;
    }
  }
  __syncthreads();

  // ---- fused c for V blocks: 8 threads per row, vectorized b128 LDS reads ----
  if (isV && a.cOut != nullptr) {
    const int row = tid >> 3, k = tid & 7;
    const int gr = row0 + row;
    const int swz = (row & 7) << 4;
    uint4 ca = *(const uint4*)((const char*)Xs + row * 256 + ((32 * k) ^ swz));
    uint4 cb = *(const uint4*)((const char*)Xs + row * 256 + ((32 * k + 16) ^ swz));
    u32 words[8] = {ca.x, ca.y, ca.z, ca.w, cb.x, cb.y, cb.z, cb.w};
    float part[4] = {};
    #pragma unroll
    for (int wi = 0; wi < 8; ++wi) {
      int d = k * 16 + wi * 2;
      float x0 = bflo(words[wi]);
      float x1 = bfhi(words[wi]);
      #pragma unroll
      for (int h = 0; h < 4; ++h) {
        part[h] = fmaf(x0, a.cU[h * 128 + d], part[h]);
        part[h] = fmaf(x1, a.cU[h * 128 + d + 1], part[h]);
      }
    }
    #pragma unroll
    for (int h = 0; h < 4; ++h) {
      #pragma unroll
      for (int o = 1; o < 8; o <<= 1) part[h] += __shfl_xor(part[h], o);
    }
    if (k == 0 && gr < n) {
      *(float4*)(a.cOut + (size_t)gr * 4) = make_float4(part[0], part[1], part[2], part[3]);
    }
  }

  const int wid = tid >> 6, lane = tid & 63;
  const int l15 = lane & 15, l4 = lane >> 4;

  s8v afr[2][4];
  #pragma unroll
  for (int rt = 0; rt < 2; ++rt) {
    int row = rt * 16 + l15;
    #pragma unroll
    for (int kk = 0; kk < 4; ++kk)
      afr[rt][kk] = *(const s8v*)((const char*)Xs + row * 256 + ((kk * 64 + l4 * 16) ^ ((row & 7) << 4)));
  }

  const u16* wbase = Wsw + ((size_t)wid * 16384) + (size_t)lane * 8;
  s8v w0[4], w1[4];
  #pragma unroll
  for (int kk = 0; kk < 4; ++kk) w0[kk] = *(const s8v*)(wbase + kk * 512);

  #pragma unroll
  for (int ctl = 0; ctl < 8; ++ctl) {
    const s8v* cw = (ctl & 1) ? w1 : w0;
    s8v* nw = (ctl & 1) ? w0 : w1;
    if (ctl + 1 < 8) {
      #pragma unroll
      for (int kk = 0; kk < 4; ++kk)
        nw[kk] = *(const s8v*)(wbase + (ctl + 1) * 2048 + kk * 512);
    }
    f4v acc0 = {}, acc1 = {};
    #pragma unroll
    for (int kk = 0; kk < 4; ++kk) {
      acc0 = __builtin_amdgcn_mfma_f32_16x16x32_bf16(cw[kk], afr[0][kk], acc0, 0, 0, 0);
      acc1 = __builtin_amdgcn_mfma_f32_16x16x32_bf16(cw[kk], afr[1][kk], acc1, 0, 0, 0);
    }
    const int colb = wid * 128 + ctl * 16 + l4 * 4;
    const float4 bb = *(const float4*)(bias + colb);
    {
      int row = l15;
      ushort4 pk;
      pk.x = f2bf(acc0[0] + bb.x); pk.y = f2bf(acc0[1] + bb.y);
      pk.z = f2bf(acc0[2] + bb.z); pk.w = f2bf(acc0[3] + bb.w);
      *(ushort4*)((char*)Os + row * 1024 + ((colb * 2) ^ ((row & 7) << 4))) = pk;
    }
    {
      int row = 16 + l15;
      ushort4 pk;
      pk.x = f2bf(acc1[0] + bb.x); pk.y = f2bf(acc1[1] + bb.y);
      pk.z = f2bf(acc1[2] + bb.z); pk.w = f2bf(acc1[3] + bb.w);
      *(ushort4*)((char*)Os + row * 1024 + ((colb * 2) ^ ((row & 7) << 4))) = pk;
    }
  }
  __syncthreads();

  const int* qr = (!isV) ? a.qrptr : nullptr;
  #pragma unroll
  for (int r = 0; r < 8; ++r) {
    int row = wid * 8 + r;
    int gr = row0 + row;
    if (gr < n) {
      if (qr != nullptr && (qr[gr + 1] - qr[gr]) < 2) continue;  // q' never read for deg<2
      uint4 val = *(const uint4*)((const char*)Os + row * 1024 + ((lane * 16) ^ ((row & 7) << 4)));
      *(uint4*)(Y + (size_t)gr * 512 + lane * 8) = val;
    }
  }
}

// ---------- skip GEMM (flat grid, STORE) ----------
__global__ __launch_bounds__(256) void gemm_skip3(const u16* xbu, const u16* xbt,
                                                  const float* xfu, const float* xft,
                                                  const u16* Wu, const u16* Wtw,
                                                  const float* bu, const float* btw,
                                                  float* aggu, float* aggt,
                                                  int fu, int ft) {
  const int bx = blockIdx.x;
  int job, lb;
  if (bx < BU) { job = 0; lb = bx; } else { job = 1; lb = bx - BU; }
  const int n = job ? NTT : NUU;
  const int bm = lb * 128;
  const u16* XB = job ? xbt : xbu;
  const float* XF = job ? xft : xfu;
  const u16* Wt = job ? Wtw : Wu;
  const float* bias = job ? btw : bu;
  float* out = job ? aggt : aggu;
  const int usexb = job ? ft : fu;

  const int wid = threadIdx.x >> 6, lane = threadIdx.x & 63;
  const int l15 = lane & 15, l4 = lane >> 4;
  const int rbase = bm + wid * 32;
  int r0 = rbase + l15;      if (r0 >= n) r0 = n - 1;
  int r1 = rbase + 16 + l15; if (r1 >= n) r1 = n - 1;
  s8v a0[4], a1[4];
  if (usexb) {
    const u16* xb0 = XB + (size_t)r0 * DD + l4 * 8;
    const u16* xb1 = XB + (size_t)r1 * DD + l4 * 8;
    #pragma unroll
    for (int kk = 0; kk < 4; ++kk) {
      a0[kk] = *(const s8v*)(xb0 + kk * 32);
      a1[kk] = *(const s8v*)(xb1 + kk * 32);
    }
  } else {
    const float* xp0 = XF + (size_t)r0 * DD + l4 * 8;
    const float* xp1 = XF + (size_t)r1 * DD + l4 * 8;
    #pragma unroll
    for (int kk = 0; kk < 4; ++kk) {
      a0[kk] = cvt_row8(xp0 + kk * 32);
      a1[kk] = cvt_row8(xp1 + kk * 32);
    }
  }

  const u16* wp = Wt + (size_t)l15 * DD + l4 * 8;
  const bool ok0 = (rbase + l15 < n), ok1 = (rbase + 16 + l15 < n);
  float* yp0 = out + (size_t)(rbase + l15) * DD + l4 * 8;
  float* yp1 = out + (size_t)(rbase + 16 + l15) * DD + l4 * 8;

  s8v w0[8], w1[8];
  #pragma unroll
  for (int kk = 0; kk < 4; ++kk) {
    w0[kk]     = *(const s8v*)(wp + kk * 32);
    w0[4 + kk] = *(const s8v*)(wp + 16 * DD + kk * 32);
  }
  #pragma unroll
  for (int p = 0; p < 4; ++p) {
    const s8v* cw = (p & 1) ? w1 : w0;
    s8v* nw = (p & 1) ? w0 : w1;
    if (p + 1 < 4) {
      const u16* wq = wp + (size_t)(2 * (p + 1)) * 16 * DD;
      #pragma unroll
      for (int kk = 0; kk < 4; ++kk) {
        nw[kk]     = *(const s8v*)(wq + kk * 32);
        nw[4 + kk] = *(const s8v*)(wq + 16 * DD + kk * 32);
      }
    }
    f4v aE0 = {}, aE1 = {}, aO0 = {}, aO1 = {};
    #pragma unroll
    for (int kk = 0; kk < 4; ++kk) {
      aE0 = __builtin_amdgcn_mfma_f32_16x16x32_bf16(cw[kk], a0[kk], aE0, 0, 0, 0);
      aE1 = __builtin_amdgcn_mfma_f32_16x16x32_bf16(cw[kk], a1[kk], aE1, 0, 0, 0);
      aO0 = __builtin_amdgcn_mfma_f32_16x16x32_bf16(cw[4 + kk], a0[kk], aO0, 0, 0, 0);
      aO1 = __builtin_amdgcn_mfma_f32_16x16x32_bf16(cw[4 + kk], a1[kk], aO1, 0, 0, 0);
    }
    const float4 bbE = *(const float4*)(bias + p * 32 + l4 * 8);
    const float4 bbO = *(const float4*)(bias + p * 32 + l4 * 8 + 4);
    if (ok0) {
      *(float4*)(yp0 + p * 32) = make_float4(aE0[0] + bbE.x, aE0[1] + bbE.y, aE0[2] + bbE.z, aE0[3] + bbE.w);
      *(float4*)(yp0 + p * 32 + 4) = make_float4(aO0[0] + bbO.x, aO0[1] + bbO.y, aO0[2] + bbO.z, aO0[3] + bbO.w);
    }
    if (ok1) {
      *(float4*)(yp1 + p * 32) = make_float4(aE1[0] + bbE.x, aE1[1] + bbE.y, aE1[2] + bbE.z, aE1[3] + bbE.w);
      *(float4*)(yp1 + p * 32 + 4) = make_float4(aO1[0] + bbO.x, aO1[1] + bbO.y, aO1[2] + bbO.z, aO1[3] + bbO.w);
    }
  }
}

// ---------- edge kernel: logits via q'.x_s + c(s); V gather; deg-1 fast path ----------
template<int XF>
__global__ __launch_bounds__(256) void edge_fused2(const u16* __restrict__ qp,
                                                   const u16* __restrict__ v,
                                                   const u16* __restrict__ xsb,
                                                   const float* __restrict__ xsf,
                                                   const float* __restrict__ cbuf,
                                                   const int* __restrict__ rptr,
                                                   const int* __restrict__ csrc,
                                                   float* __restrict__ agg,
                                                   int nd, int qs32) {
  int node = (int)(((size_t)blockIdx.x * 256 + threadIdx.x) >> 6);
  int lane = threadIdx.x & 63;
  if (node >= nd) return;
  int e0 = rptr[node], e1 = rptr[node + 1];
  if (e0 == e1) return;
  const int g = lane >> 4, i = lane & 15;
  float acc[8];

  if (e1 - e0 == 1) {
    int s = csrc[e0];
    const u32* vp = (const u32*)v + (size_t)s * 256 + lane * 4;
    #pragma unroll
    for (int j = 0; j < 4; ++j) { u32 u = vp[j]; acc[2 * j] = bflo(u); acc[2 * j + 1] = bfhi(u); }
  } else {
    u32 qv[4];
    {
      const u32* qq = (const u32*)qp + (size_t)node * qs32 + g * 64 + i * 4;
      #pragma unroll
      for (int j = 0; j < 4; ++j) qv[j] = qq[j];
    }
    float m = -1e30f, z = 0.f;
    #pragma unroll
    for (int j = 0; j < 8; ++j) acc[j] = 0.f;

    int s_cur = csrc[e0];
    u32 xc[4]; float xf[8];
    if (XF) {
      const u32* xp = (const u32*)xsb + (size_t)s_cur * 64 + i * 4;
      #pragma unroll
      for (int j = 0; j < 4; ++j) xc[j] = xp[j];
    } else {
      const float* xp = xsf + (size_t)s_cur * 128 + i * 8;
      #pragma unroll
      for (int j = 0; j < 8; ++j) xf[j] = xp[j];
    }

    for (int e = e0; e < e1; ++e) {
      u32 vcur[4];
      {
        const u32* vp = (const u32*)v + (size_t)s_cur * 256 + lane * 4;
        #pragma unroll
        for (int j = 0; j < 4; ++j) vcur[j] = vp[j];
      }
      float cs = cbuf[(size_t)s_cur * 4 + g];
      const bool has = (e + 1 < e1);
      int s_nxt = csrc[has ? e + 1 : e0];
      u32 xn[4]; float xnf[8];
      if (XF) {
        const u32* xp = (const u32*)xsb + (size_t)s_nxt * 64 + i * 4;
        #pragma unroll
        for (int j = 0; j < 4; ++j) xn[j] = xp[j];
      } else {
        const float* xp = xsf + (size_t)s_nxt * 128 + i * 8;
        #pragma unroll
        for (int j = 0; j < 8; ++j) xnf[j] = xp[j];
      }

      float dot = 0.f;
      if (XF) {
        #pragma unroll
        for (int j = 0; j < 4; ++j)
          dot += bflo(qv[j]) * bflo(xc[j]) + bfhi(qv[j]) * bfhi(xc[j]);
      } else {
        #pragma unroll
        for (int j = 0; j < 4; ++j)
          dot += bflo(qv[j]) * xf[2 * j] + bfhi(qv[j]) * xf[2 * j + 1];
      }
      dot += __shfl_xor(dot, 1);
      dot += __shfl_xor(dot, 2);
      dot += __shfl_xor(dot, 4);
      dot += __shfl_xor(dot, 8);
      float lg = dot * 0.08838834764831845f + cs;
      float w;
      if (lg > m) {
        float sc = __expf(m - lg);
        z *= sc;
        #pragma unroll
        for (int j = 0; j < 8; ++j) acc[j] *= sc;
        m = lg; w = 1.f;
      } else {
        w = __expf(lg - m);
      }
      z += w;
      #pragma unroll
      for (int j = 0; j < 4; ++j) {
        acc[2 * j]     += w * bflo(vcur[j]);
        acc[2 * j + 1] += w * bfhi(vcur[j]);
      }
      if (has) {
        s_cur = s_nxt;
        if (XF) {
          #pragma unroll
          for (int j = 0; j < 4; ++j) xc[j] = xn[j];
        } else {
          #pragma unroll
          for (int j = 0; j < 8; ++j) xf[j] = xnf[j];
        }
      }
    }
    float iz = 1.f / z;
    #pragma unroll
    for (int j = 0; j < 8; ++j) acc[j] *= iz;
  }

  #pragma unroll
  for (int j = 0; j < 8; ++j) acc[j] *= 0.25f;
  #pragma unroll
  for (int o = 16; o < 64; o <<= 1) {
    #pragma unroll
    for (int j = 0; j < 8; ++j) acc[j] += __shfl_xor(acc[j], o);
  }
  if (lane < 16) {
    float* op = agg + (size_t)node * DD + lane * 8;
    #pragma unroll
    for (int j = 0; j < 8; ++j) op[j] += acc[j];
  }
}

// ---------- l0-tu shortcut: uniform softmax over broadcast K/V ----------
__global__ __launch_bounds__(256) void add_bcast4(const u16* __restrict__ v,
                                                  const int* __restrict__ rptr,
                                                  float* __restrict__ agg, int nd) {
  int node = (int)(((size_t)blockIdx.x * 256 + threadIdx.x) >> 6);
  int lane = threadIdx.x & 63;
  if (node >= nd) return;
  if (rptr[node + 1] <= rptr[node]) return;
  const u32* vp = (const u32*)v;   // row 0
  float a0 = 0.f, a1 = 0.f;
  #pragma unroll
  for (int h = 0; h < 4; ++h) {
    u32 u = vp[h * 64 + lane];
    a0 += bflo(u); a1 += bfhi(u);
  }
  float* op = agg + (size_t)node * DD + 2 * lane;
  op[0] += 0.25f * a0;
  op[1] += 0.25f * a1;
}

// ---------- LayerNorm + residual (explicit residual src, bf16 mirror writes) ----------
__global__ __launch_bounds__(256) void ln2(const float* __restrict__ aggu,
                                           const float* __restrict__ aggt,
                                           const float* __restrict__ g2,
                                           const float* __restrict__ b2,
                                           const float* __restrict__ ru,
                                           const float* __restrict__ rt,
                                           int rts,
                                           float* __restrict__ xu,
                                           float* __restrict__ xt,
                                           u16* __restrict__ xbu,
                                           u16* __restrict__ xbt,
                                           int wbu, int wbt) {
  int wid = (int)(((size_t)blockIdx.x * 256 + threadIdx.x) >> 6);
  int lane = threadIdx.x & 63;
  if (wid >= NUU + NTT) return;
  const float* ap; float* xp; const float* g; const float* b; u16* xbp; int wb;
  const float* rp;
  if (wid < NUU) {
    ap = aggu + (size_t)wid * DD; xp = xu + (size_t)wid * DD;
    rp = ru + (size_t)wid * DD;
    xbp = xbu ? xbu + (size_t)wid * DD : nullptr; g = g2; b = b2; wb = wbu;
  } else {
    int t = wid - NUU;
    ap = aggt + (size_t)t * DD; xp = xt + (size_t)t * DD;
    rp = rt + (size_t)t * rts;
    xbp = xbt ? xbt + (size_t)t * DD : nullptr; g = g2 + DD; b = b2 + DD; wb = wbt;
  }
  float2 va = *(const float2*)(ap + 2 * lane);
  float v0 = va.x, v1 = va.y;
  float s = v0 + v1;
  #pragma unroll
  for (int o = 1; o < 64; o <<= 1) s += __shfl_xor(s, o);
  float mean = s * (1.0f / DD);
  float d0 = v0 - mean, d1 = v1 - mean;
  float sq = d0 * d0 + d1 * d1;
  #pragma unroll
  for (int o = 1; o < 64; o <<= 1) sq += __shfl_xor(sq, o);
  float rstd = rsqrtf(sq * (1.0f / DD) + 1e-5f);
  float2 xv = *(const float2*)(rp + 2 * lane);
  float2 gv = *(const float2*)(g + 2 * lane);
  float2 bv = *(const float2*)(b + 2 * lane);
  float n0 = gv.x * d0 * rstd + bv.x + xv.x;
  float n1 = gv.y * d1 * rstd + bv.y + xv.y;
  *(float2*)(xp + 2 * lane) = make_float2(n0, n1);
  if (wb) {
    *(u32*)(xbp + 2 * lane) = (u32)f2bf(n0) | ((u32)f2bf(n1) << 16);
  }
}

extern "C" void kernel_launch(void* const* d_in, const int* in_sizes, int n_in,
                              void* d_out, int out_size, void* d_ws, size_t ws_size,
                              hipStream_t stream) {
  const float* emb_user = (const float*)d_in[0];
  const float* tv_tweet = (const float*)d_in[1];
  const float* W_qkv  = (const float*)d_in[2];
  const float* b_qkv  = (const float*)d_in[3];
  const float* W_skip = (const float*)d_in[4];
  const float* b_skip = (const float*)d_in[5];
  const float* ln_g   = (const float*)d_in[6];
  const float* ln_b   = (const float*)d_in[7];
  const int* edges[3] = { (const int*)d_in[8], (const int*)d_in[9], (const int*)d_in[10] };

  float* x_user  = (float*)d_out;
  float* x_tweet = x_user + (size_t)NUU * DD;

  // ---- workspace layout (identical to R12/R14/R15/R16) ----
  const size_t fixed = 786432 + 131072 + 2048 + 786432 + 12288 + 2048 + 1600000
                     + 76800000 + (size_t)3 * 400032 + (size_t)3 * 400000 + 4800
                     + 153600000 + 4096;
  int XBU = 0, XBT = 0;
  if      (ws_size >= fixed + 38400000) { XBU = 1; XBT = 1; }
  else if (ws_size >= fixed + 25600000) { XBT = 1; }

  char* w = (char*)d_ws;
  u16* Wtv = (u16*)w;        w += 786432;
  u16* WtsC = (u16*)w;       w += 131072;
  float* bskC = (float*)w;   w += 2048;
  u16* Mwt = (u16*)w;        w += 786432;
  float* Uw = (float*)w;     w += 12288;
  float* zeros = (float*)w;  w += 2048;
  float* cbuf = (float*)w;   w += 1600000;
  float* agg_u = (float*)w;  w += (size_t)NUU * DD * 4;
  float* agg_t = (float*)w;  w += (size_t)NTT * DD * 4;
  int* rptrA[3]; int* csrcA[3];
  for (int r = 0; r < 3; ++r) { rptrA[r] = (int*)w; w += 400032; }
  for (int r = 0; r < 3; ++r) { csrcA[r] = (int*)w; w += 400000; }
  int* bsumA = (int*)w;      w += 4800;
  u16* xb_user = nullptr; u16* xb_tweet = nullptr;
  if (XBT) { xb_tweet = (u16*)w; w += (size_t)NTT * DD * 2; }
  if (XBU) { xb_user = (u16*)w;  w += (size_t)NUU * DD * 2; }
  u16* arena = (u16*)w;
  int* cntA[3];
  cntA[0] = (int*)arena; cntA[1] = cntA[0] + 100000; cntA[2] = cntA[0] + 200000;

  init_x2<<<(19500000 + 255) / 256, 256, 0, stream>>>(emb_user, tv_tweet, x_user, x_tweet,
                                                      cntA[0], xb_user, xb_tweet, XBU, XBT);
  conv_w<<<(6 * 65536 + 255) / 256, 256, 0, stream>>>(W_qkv, W_skip, b_skip,
                                                      Wtv, WtsC, bskC, zeros);
  mk_m2<<<dim3(24, 8), 256, 0, stream>>>(W_qkv, b_qkv, Mwt, Uw);

  hist3<<<(3 * EE + 255) / 256, 256, 0, stream>>>(edges[0], edges[1], edges[2],
                                                  cntA[0], cntA[1], cntA[2]);
  bsum3<<<783, 256, 0, stream>>>(cntA[0], cntA[1], cntA[2], bsumA);
  bscan3<<<3, 256, 0, stream>>>(bsumA);
  rptr3<<<783, 256, 0, stream>>>(cntA[0], cntA[1], cntA[2], bsumA, rptrA[0], rptrA[1], rptrA[2]);
  fill3<<<(3 * EE + 255) / 256, 256, 0, stream>>>(edges[0], edges[1], edges[2],
                                                  cntA[0], cntA[1], cntA[2],
                                                  csrcA[0], csrcA[1], csrcA[2]);

  const int stt[3] = {0, 0, 1}, dtt[3] = {0, 1, 0};
  const int cnt2[2] = {NUU, NTT};
  float* xs[2]   = {x_user, x_tweet};
  u16* xbs[2]    = {xb_user, xb_tweet};
  const int xbf[2] = {XBU, XBT};
  float* aggs[2] = {agg_u, agg_t};

  for (int l = 0; l < 2; ++l) {
    gemm_skip3<<<BU + BT, 256, 0, stream>>>(
        xb_user, xb_tweet, x_user, x_tweet,
        WtsC + (size_t)(2 * l) * 128 * 128, WtsC + (size_t)(2 * l + 1) * 128 * 128,
        bskC + (size_t)(2 * l) * 128, bskC + (size_t)(2 * l + 1) * 128,
        agg_u, agg_t, XBU, XBT);

    for (int r = 0; r < 3; ++r) {
      const int st = stt[r], dt = dtt[r];
      const int ns = cnt2[st], nd = cnt2[dt];
      const int rel = l * 3 + r;
      const bool qDeg = (l == 0 && dt == 1);   // ut-l0: broadcast dst
      const bool uniSM = (l == 0 && st == 1);  // tu-l0: broadcast src -> uniform softmax

      const int nq_eff = uniSM ? 0 : (qDeg ? 1 : nd);
      const int nv_eff = uniSM ? 1 : ns;
      u16* qb_r = arena;
      u16* vb_r = arena + (size_t)nq_eff * HCC;

      GRel3 ga;
      ga.Xqb = xbs[dt]; ga.Xqf = xs[dt]; ga.xbq = xbf[dt];
      ga.Xvb = xbs[st]; ga.Xvf = xs[st]; ga.xbv = xbf[st];
      ga.Wq = Mwt + (size_t)rel * 65536;
      ga.Wv = Wtv + (size_t)rel * 65536;
      ga.bzq = zeros;
      ga.bzv = b_qkv + (size_t)(rel * 3 + 2) * HCC;
      ga.cU = Uw + (size_t)rel * 512;
      ga.cOut = uniSM ? nullptr : cbuf;
      // q' store filter: only valid when q' rows map 1:1 to dst nodes
      ga.qrptr = (qDeg || uniSM) ? nullptr : rptrA[r];
      ga.oq = qb_r; ga.ov = vb_r;
      ga.nq = nq_eff; ga.nv = nv_eff;
      ga.bq = (nq_eff + 31) / 32; ga.bv = (nv_eff + 31) / 32;
      gemm_rel3<<<ga.bq + ga.bv, 256, 0, stream>>>(ga);

      const int eblk = (nd + 3) / 4;
      if (uniSM) {
        add_bcast4<<<eblk, 256, 0, stream>>>(vb_r, rptrA[r], aggs[dt], nd);
      } else {
        const int qs32 = qDeg ? 0 : 256;
        if (xbf[st])
          edge_fused2<1><<<eblk, 256, 0, stream>>>(qb_r, vb_r, xbs[st], xs[st], cbuf,
                                                   rptrA[r], csrcA[r], aggs[dt], nd, qs32);
        else
          edge_fused2<0><<<eblk, 256, 0, stream>>>(qb_r, vb_r, xbs[st], xs[st], cbuf,
                                                   rptrA[r], csrcA[r], aggs[dt], nd, qs32);
      }
    }
    const float* ru = (l == 0 && XBU) ? emb_user : x_user;
    const float* rt = (l == 0 && XBT) ? tv_tweet : x_tweet;
    const int rts = (l == 0 && XBT) ? 0 : DD;
    ln2<<<(NUU + NTT + 3) / 4, 256, 0, stream>>>(agg_u, agg_t,
                                                 ln_g + (size_t)l * 2 * DD,
                                                 ln_b + (size_t)l * 2 * DD,
                                                 ru, rt, rts,
                                                 x_user, x_tweet,
                                                 xb_user, xb_tweet,
                                                 XBU && l == 0, XBT && l == 0);
  }
}